// Round 14
// baseline (1074.907 us; speedup 1.0000x reference)
//
#include <hip/hip_runtime.h>
#include <hip/hip_bf16.h>
#include <math.h>

// B=4, C=16 -> N=64 images; E=256; H=W=32 -> P=1024/img, 65536 total; I=256; HID=1024; L=4
// ws layout (~132.6MB):
//   hb   bf16[64][256][1024]  @0      32MB   residual stream (NCHW, bf16)
//   tb   bf16[65536][256]     @32MB   32MB   LN'd NHWC, SLOT-SWIZZLED (s^=(px&7) per 128B blk);
//                                            final-layer ht (unswizzled) overwrites consumed rows
//   u    bf16[32768][1024]    @64MB   64MB   hidden chunk (32 images, 2 chunks/layer)
//     overlays in u region: tc bf16[64][256][1024]; Wt @64MB; xTb @72MB (prologue)
//   w1b  @128MB 2MB (SLOT-SWIZZLED by d&7); w2b @130MB 2MB (plain); gx @132MB; nx; cvec; flag

typedef __attribute__((ext_vector_type(8))) __bf16 bf16x8;
typedef __attribute__((ext_vector_type(4))) float f32x4;

__device__ __forceinline__ short f2bf(float f) {
  unsigned u = __float_as_uint(f);
  unsigned r = (u + 0x7FFFu + ((u >> 16) & 1u)) >> 16;
  return (short)r;
}
__device__ __forceinline__ float bf2f(short s) {
  return __uint_as_float(((unsigned)(unsigned short)s) << 16);
}
__device__ __forceinline__ int pack2(short a, short b) {
  return (int)(unsigned short)a | ((int)(unsigned short)b << 16);
}
// tanh-approx GELU, sigmoid form, hardware rcp (v_rcp_f32; ~1e-7 rel err)
__device__ __forceinline__ float gelu(float x) {
  float t = __builtin_fmaf(0.0713548162f * x * x, x, 1.59576912f * x);
  return x * __builtin_amdgcn_rcpf(1.f + __expf(-t));
}

__device__ __forceinline__ void gload16(const short* g, short* l) {
  __builtin_amdgcn_global_load_lds(
      (const __attribute__((address_space(1))) void*)(g),
      (__attribute__((address_space(3))) void*)(l), 16, 0, 0);
}

__device__ __forceinline__ float block_sum(float v, float* red) {
#pragma unroll
  for (int o = 32; o > 0; o >>= 1) v += __shfl_down(v, o);
  int lane = threadIdx.x & 63, w = threadIdx.x >> 6;
  int nw = blockDim.x >> 6;
  if (lane == 0) red[w] = v;
  __syncthreads();
  if (threadIdx.x == 0) {
    float s = 0.f;
    for (int i = 0; i < nw; ++i) s += red[i];
    red[0] = s;
  }
  __syncthreads();
  float s = red[0];
  __syncthreads();
  return s;
}

// ======================= MFMA GEMM core (BK=32, linear LDS; m97 structure) ==============
template <int K>
__device__ __forceinline__ void gemm_core(const short* __restrict__ A, const short* __restrict__ Bt,
                                          int m0, int n0, short* As, short* Bs, f32x4 acc[4][4]) {
  const int tid = threadIdx.x;
  const int lane = tid & 63, wave = tid >> 6;
  const int wr = wave >> 1, wc = wave & 1;
  const int lr = lane & 15, kg = lane >> 4;
#pragma unroll
  for (int mi = 0; mi < 4; ++mi)
#pragma unroll
    for (int ni = 0; ni < 4; ++ni) acc[mi][ni] = f32x4{0.f, 0.f, 0.f, 0.f};
  const int sr = lane >> 2, sc = (lane & 3) * 8;
  const int ra0 = wave * 16, ra1 = wave * 16 + 64;
  const short* Ab = A + (size_t)m0 * K;
  const short* Bb = Bt + (size_t)n0 * K;
  for (int k0 = 0; k0 < K; k0 += 32) {
    gload16(Ab + (size_t)(ra0 + sr) * K + k0 + sc, As + ra0 * 32);
    gload16(Ab + (size_t)(ra1 + sr) * K + k0 + sc, As + ra1 * 32);
    gload16(Bb + (size_t)(ra0 + sr) * K + k0 + sc, Bs + ra0 * 32);
    gload16(Bb + (size_t)(ra1 + sr) * K + k0 + sc, Bs + ra1 * 32);
    __syncthreads();
    bf16x8 af[4], bfr[4];
#pragma unroll
    for (int mi = 0; mi < 4; ++mi) af[mi] = *(const bf16x8*)&As[(wr * 64 + mi * 16 + lr) * 32 + kg * 8];
#pragma unroll
    for (int ni = 0; ni < 4; ++ni) bfr[ni] = *(const bf16x8*)&Bs[(wc * 64 + ni * 16 + lr) * 32 + kg * 8];
#pragma unroll
    for (int mi = 0; mi < 4; ++mi)
#pragma unroll
      for (int ni = 0; ni < 4; ++ni)
        acc[mi][ni] = __builtin_amdgcn_mfma_f32_16x16x32_bf16(af[mi], bfr[ni], acc[mi][ni], 0, 0, 0);
    __syncthreads();
  }
}

// ======================= MFMA GEMM core (BK=64, swizzled operands) ======================
// A,Bt pre-swizzled in GLOBAL memory: 16B slot j of each 128B block of row r holds slot j^(r&7).
template <int K>
__device__ __forceinline__ void gemm_core_k64(const short* __restrict__ A, const short* __restrict__ Bt,
                                              int m0, int n0, short* As, short* Bs, f32x4 acc[4][4]) {
  const int tid = threadIdx.x;
  const int lane = tid & 63, wave = tid >> 6;
  const int wr = wave >> 1, wc = wave & 1;
  const int lr = lane & 15, kg = lane >> 4;
#pragma unroll
  for (int mi = 0; mi < 4; ++mi)
#pragma unroll
    for (int ni = 0; ni < 4; ++ni) acc[mi][ni] = f32x4{0.f, 0.f, 0.f, 0.f};
  const int sr = lane >> 3;          // 0..7
  const int sc = (lane & 7) * 8;     // 0..56
  const short* Ab = A + (size_t)m0 * K;
  const short* Bb = Bt + (size_t)n0 * K;
  for (int k0 = 0; k0 < K; k0 += 64) {
#pragma unroll
    for (int j = 0; j < 4; ++j) {
      int r = wave * 8 + j * 32;
      gload16(Ab + (size_t)(r + sr) * K + k0 + sc, As + r * 64);
      gload16(Bb + (size_t)(r + sr) * K + k0 + sc, Bs + r * 64);
    }
    __syncthreads();
#pragma unroll
    for (int ks = 0; ks < 2; ++ks) {
      bf16x8 af[4], bfr[4];
#pragma unroll
      for (int mi = 0; mi < 4; ++mi) {
        int R = wr * 64 + mi * 16 + lr;
        int s = ks * 4 + kg;
        af[mi] = *(const bf16x8*)&As[R * 64 + ((s ^ (R & 7)) << 3)];
      }
#pragma unroll
      for (int ni = 0; ni < 4; ++ni) {
        int R = wc * 64 + ni * 16 + lr;
        int s = ks * 4 + kg;
        bfr[ni] = *(const bf16x8*)&Bs[R * 64 + ((s ^ (R & 7)) << 3)];
      }
#pragma unroll
      for (int mi = 0; mi < 4; ++mi)
#pragma unroll
        for (int ni = 0; ni < 4; ++ni)
          acc[mi][ni] = __builtin_amdgcn_mfma_f32_16x16x32_bf16(af[mi], bfr[ni], acc[mi][ni], 0, 0, 0);
    }
    __syncthreads();
  }
}

// ======================= MFMA GEMM core, 128(m) x 64(n) tile (BK=32, linear) ============
template <int K>
__device__ __forceinline__ void gemm_core_n64(const short* __restrict__ A, const short* __restrict__ Bt,
                                              int m0, int n0, short* As, short* Bs, f32x4 acc[4][2]) {
  const int tid = threadIdx.x;
  const int lane = tid & 63, wave = tid >> 6;
  const int wr = wave >> 1, wc = wave & 1;
  const int lr = lane & 15, kg = lane >> 4;
#pragma unroll
  for (int mi = 0; mi < 4; ++mi)
#pragma unroll
    for (int ni = 0; ni < 2; ++ni) acc[mi][ni] = f32x4{0.f, 0.f, 0.f, 0.f};
  const int sr = lane >> 2, sc = (lane & 3) * 8;
  const int ra0 = wave * 16, ra1 = wave * 16 + 64;
  const short* Ab = A + (size_t)m0 * K;
  const short* Bb = Bt + (size_t)n0 * K;
  for (int k0 = 0; k0 < K; k0 += 32) {
    gload16(Ab + (size_t)(ra0 + sr) * K + k0 + sc, As + ra0 * 32);
    gload16(Ab + (size_t)(ra1 + sr) * K + k0 + sc, As + ra1 * 32);
    gload16(Bb + (size_t)(ra0 + sr) * K + k0 + sc, Bs + ra0 * 32);
    __syncthreads();
    bf16x8 af[4], bfr[2];
#pragma unroll
    for (int mi = 0; mi < 4; ++mi) af[mi] = *(const bf16x8*)&As[(wr * 64 + mi * 16 + lr) * 32 + kg * 8];
#pragma unroll
    for (int ni = 0; ni < 2; ++ni) bfr[ni] = *(const bf16x8*)&Bs[(wc * 32 + ni * 16 + lr) * 32 + kg * 8];
#pragma unroll
    for (int mi = 0; mi < 4; ++mi)
#pragma unroll
      for (int ni = 0; ni < 2; ++ni)
        acc[mi][ni] = __builtin_amdgcn_mfma_f32_16x16x32_bf16(af[mi], bfr[ni], acc[mi][ni], 0, 0, 0);
    __syncthreads();
  }
}

// ======================= prep kernels =======================
// w1b stored SLOT-SWIZZLED: 16B slot j within each 64-short block moves to j ^ (d&7).
__global__ void k_cvt_w(const float* __restrict__ fc1w, const float* __restrict__ fc2w,
                        short* __restrict__ w1b, short* __restrict__ w2b) {
  int i = blockIdx.x * 256 + threadIdx.x;  // 4*262144
  int d7 = (i >> 8) & 7;
  int e = i & 255;
  int es = (e & 0xC0) | (((((e >> 3) & 7) ^ d7)) << 3) | (e & 7);
  w1b[(i & ~255) | es] = f2bf(fc1w[i]);
  w2b[i] = f2bf(fc2w[i]);
}

// x [4][256 i][1024 p] f32 -> xTb [4][1024 p][256 i] bf16
__global__ void k_prep_xt(const float* __restrict__ x, short* __restrict__ xTb) {
  __shared__ float tile[32][33];
  int tx = threadIdx.x & 31, ty = threadIdx.x >> 5;
  int p0 = blockIdx.x * 32, i0 = blockIdx.y * 32, b = blockIdx.z;
#pragma unroll
  for (int r = 0; r < 4; ++r) {
    int i = ty + r * 8;
    tile[i][tx] = x[((size_t)b * 256 + i0 + i) * 1024 + p0 + tx];
  }
  __syncthreads();
#pragma unroll
  for (int r = 0; r < 4; ++r) {
    int p = ty + r * 8;
    xTb[((size_t)b * 1024 + p0 + p) * 256 + i0 + tx] = f2bf(tile[tx][p]);
  }
}

// hk_w gather+transpose: Wt[n][e][i] bf16 = hkw[idx[n]][i][e]
__global__ void k_prep_wt(const float* __restrict__ hkw, const int* __restrict__ idx,
                          short* __restrict__ Wt) {
  __shared__ float tile[32][33];
  int tx = threadIdx.x & 31, ty = threadIdx.x >> 5;
  int e0 = blockIdx.x * 32, i0 = blockIdx.y * 32, n = blockIdx.z;
  int ch = idx[n];
#pragma unroll
  for (int r = 0; r < 4; ++r) {
    int i = ty + r * 8;
    tile[i][tx] = hkw[(size_t)ch * 65536 + (size_t)(i0 + i) * 256 + e0 + tx];
  }
  __syncthreads();
#pragma unroll
  for (int r = 0; r < 4; ++r) {
    int e = ty + r * 8;
    Wt[((size_t)n * 256 + e0 + e) * 256 + i0 + tx] = f2bf(tile[tx][e]);
  }
}

// flag[l] = any(grn_g != 0); cvec[l][e] = sum_d fc2_w[l][e][d]*grn_b[l][d]
__global__ void k_prep_misc(const float* __restrict__ grng, const float* __restrict__ grnb,
                            const float* __restrict__ fc2w, int* __restrict__ flag,
                            float* __restrict__ cvec) {
  __shared__ float red[8];
  int l = blockIdx.y;
  if (blockIdx.x == 0) {
    float any = 0.f;
    for (int d = threadIdx.x; d < 1024; d += 256)
      any += (grng[l * 1024 + d] != 0.f) ? 1.f : 0.f;
    float tot = block_sum(any, red);
    if (threadIdx.x == 0) flag[l] = (tot > 0.f) ? 1 : 0;
  } else {
    int e = blockIdx.x - 1;
    float s = 0.f;
    for (int d = threadIdx.x; d < 1024; d += 256)
      s += fc2w[((size_t)(l * 256 + e) << 10) + d] * grnb[l * 1024 + d];
    float tot = block_sum(s, red);
    if (threadIdx.x == 0) cvec[l * 256 + e] = tot;
  }
}

// ======================= hyper GEMM: hb[n][e][p] = Wt[n]@xTb[b] + hkb (bf16 out) =========
__global__ void __launch_bounds__(256) k_hypm(const short* __restrict__ Wt, const short* __restrict__ xTb,
                                              const int* __restrict__ idx, const float* __restrict__ hkb,
                                              short* __restrict__ hb) {
  __shared__ short As[4096], Bs[4096];
  f32x4 acc[4][4];
  int n = blockIdx.z;
  int m0 = blockIdx.y * 128, n0 = blockIdx.x * 128;
  gemm_core<256>(Wt + (size_t)n * 65536, xTb + (size_t)(n >> 4) * 262144, m0, n0, As, Bs, acc);
  int ch = idx[n];
  const int lane = threadIdx.x & 63, wave = threadIdx.x >> 6;
  const int wr = wave >> 1, wc = wave & 1, lr = lane & 15, kg = lane >> 4;
#pragma unroll
  for (int mi = 0; mi < 4; ++mi) {
    int ebase = m0 + wr * 64 + mi * 16 + kg * 4;
#pragma unroll
    for (int ni = 0; ni < 4; ++ni) {
      int p = n0 + wc * 64 + ni * 16 + lr;
      f32x4 v = acc[mi][ni];
#pragma unroll
      for (int r = 0; r < 4; ++r)
        hb[((size_t)(n * 256 + ebase + r) << 10) + p] = f2bf(v[r] + hkb[ch * 256 + ebase + r]);
    }
  }
}

// ======================= depthwise 7x7 conv: b128 LDS reads, 8px/thread ==================
// grid (256 e, 64 n); block 128 (2 waves). sm data at [y+3][x+4] (left halo 4 -> aligned b128).
__global__ void __launch_bounds__(128) k_conv(const short* __restrict__ hb, const float* __restrict__ dww,
                                              const float* __restrict__ dwb, short* __restrict__ tc, int l) {
  __shared__ float sm[38][40];   // 6.08KB
  int e = blockIdx.x, n = blockIdx.y;
  const short* plane = hb + (((size_t)(n * 256 + e)) << 10);
  const float* wv = dww + ((size_t)(l * 256 + e)) * 49;
  float w[49];
#pragma unroll
  for (int i = 0; i < 49; ++i) w[i] = wv[i];  // uniform -> scalar loads
  int tid = threadIdx.x;
  float* smf = &sm[0][0];
  for (int i = tid; i < 380; i += 128) {
    float4 z = make_float4(0.f, 0.f, 0.f, 0.f);
    *(float4*)&smf[i * 4] = z;
  }
  __syncthreads();
  {
    const int* plane32 = (const int*)plane;
    for (int i = tid; i < 512; i += 128) {
      int v = plane32[i];
      int p = i * 2;
      int iy = p >> 5, ix = p & 31;
      sm[iy + 3][ix + 4] = bf2f((short)(v & 0xffff));
      sm[iy + 3][ix + 5] = bf2f((short)(v >> 16));
    }
  }
  __syncthreads();
  int y = tid >> 2, x0 = (tid & 3) * 8;
  float bias = dwb[l * 256 + e];
  float acc[8];
#pragma unroll
  for (int i = 0; i < 8; ++i) acc[i] = bias;
#pragma unroll
  for (int r = 0; r < 7; ++r) {
    // aligned b128 reads: cols x0..x0+15 cover taps x0+1..x0+14
    float4 v0 = *(const float4*)&sm[y + r][x0];
    float4 v1 = *(const float4*)&sm[y + r][x0 + 4];
    float4 v2 = *(const float4*)&sm[y + r][x0 + 8];
    float4 v3 = *(const float4*)&sm[y + r][x0 + 12];
    float c[16] = {v0.x, v0.y, v0.z, v0.w, v1.x, v1.y, v1.z, v1.w,
                   v2.x, v2.y, v2.z, v2.w, v3.x, v3.y, v3.z, v3.w};
#pragma unroll
    for (int dx = 0; dx < 7; ++dx) {
      float wk = w[r * 7 + dx];
#pragma unroll
      for (int i = 0; i < 8; ++i) acc[i] = __builtin_fmaf(c[i + dx + 1], wk, acc[i]);
    }
  }
  short o[8];
#pragma unroll
  for (int i = 0; i < 8; ++i) o[i] = f2bf(acc[i]);
  int4 pk;
  pk.x = pack2(o[0], o[1]); pk.y = pack2(o[2], o[3]);
  pk.z = pack2(o[4], o[5]); pk.w = pack2(o[6], o[7]);
  *(int4*)&tc[(((size_t)(n * 256 + e)) << 10) + y * 32 + x0] = pk;
}

// ======================= LayerNorm + NCHW->NHWC transpose (tc -> tb, SWIZZLED store) =====
__global__ void __launch_bounds__(256) k_ln(const short* __restrict__ tc, const float* __restrict__ lng,
                                            const float* __restrict__ lnb, short* __restrict__ tb,
                                            float* __restrict__ gx, const int* __restrict__ flag, int l) {
  __shared__ float smT[32][261];
  __shared__ float muS[32], rsS[32];
  int n = blockIdx.y, p0 = blockIdx.x * 32;
  int tid = threadIdx.x;
  if (blockIdx.x == 0 && flag[l] != 0) {
#pragma unroll
    for (int r = 0; r < 4; ++r) gx[n * 1024 + r * 256 + tid] = 0.f;
  }
  const short* base = tc + ((size_t)n << 18) + p0;
  for (int i = tid; i < 8192; i += 256) {
    int e = i >> 5, p = i & 31;
    smT[p][e] = bf2f(base[(e << 10) + p]);
  }
  __syncthreads();
  {
    int j = tid & 7, p = tid >> 3;
    float s = 0.f, q = 0.f;
#pragma unroll
    for (int i = 0; i < 32; ++i) {
      float v = smT[p][j + i * 8];
      s += v; q += v * v;
    }
    s += __shfl_xor(s, 1); q += __shfl_xor(q, 1);
    s += __shfl_xor(s, 2); q += __shfl_xor(q, 2);
    s += __shfl_xor(s, 4); q += __shfl_xor(q, 4);
    if (j == 0) {
      float mu = s * (1.f / 256.f);
      float var = q * (1.f / 256.f) - mu * mu;
      muS[p] = mu;
      rsS[p] = rsqrtf(fmaxf(var, 0.f) + 1e-5f);
    }
  }
  __syncthreads();
  for (int i = tid; i < 8192; i += 256) {
    int p = i >> 8, e = i & 255;
    int px = n * 1024 + p0 + p;
    float v = (smT[p][e] - muS[p]) * rsS[p] * lng[l * 256 + e] + lnb[l * 256 + e];
    int es = (e & 0xC0) | ((((e >> 3) & 7) ^ (px & 7)) << 3) | (e & 7);
    tb[((size_t)px) * 256 + es] = f2bf(v);
  }
}

// ======================= GRN general path (flag-gated; no-op for this data) ==============
__global__ void __launch_bounds__(256) k_gx1(const short* __restrict__ w1b, const short* __restrict__ tb,
                                             const float* __restrict__ fc1b, float* __restrict__ gx,
                                             const int* __restrict__ flag, int l) {
  if (flag[l] == 0) return;
  __shared__ short As[8192], Bs[8192];
  f32x4 acc[4][4];
  int m0 = blockIdx.y * 128, n0 = blockIdx.x * 128;
  gemm_core_k64<256>(w1b + (size_t)l * 262144, tb, m0, n0, As, Bs, acc);
  const int lane = threadIdx.x & 63, wave = threadIdx.x >> 6;
  const int wr = wave >> 1, kg = lane >> 4;
  int n = (n0 >> 10);
#pragma unroll
  for (int mi = 0; mi < 4; ++mi) {
    int dbase = m0 + wr * 64 + mi * 16 + kg * 4;
#pragma unroll
    for (int ni = 0; ni < 4; ++ni) {
      f32x4 v = acc[mi][ni];
#pragma unroll
      for (int r = 0; r < 4; ++r) {
        float g = gelu(v[r] + fc1b[l * 1024 + dbase + r]);
        atomicAdd(&gx[n * 1024 + dbase + r], g * g);
      }
    }
  }
}

__global__ void k_nx(const float* __restrict__ gx, float* __restrict__ nx,
                     const int* __restrict__ flag, int l) {
  int n = blockIdx.x, tid = threadIdx.x;
  if (flag[l] == 0) {
    for (int d = tid; d < 1024; d += 256) nx[n * 1024 + d] = 0.f;
    return;
  }
  __shared__ float red[8];
  __shared__ float sv[1024];
  float s = 0.f;
  for (int d = tid; d < 1024; d += 256) {
    float v = sqrtf(gx[n * 1024 + d]);
    sv[d] = v; s += v;
  }
  float tot = block_sum(s, red);
  float mean = tot * (1.f / 1024.f);
  for (int d = tid; d < 1024; d += 256) nx[n * 1024 + d] = sv[d] / (mean + 1e-6f);
}

// ======================= fc1 (BK=64 swizzled core): u = gelu(tb@W1^T+b1)*(1+g*nx) ========
// 1D grid 2048 = 8 XCD x 32 n-tiles x 8 m-tiles
__global__ void __launch_bounds__(256) k_fc1(const short* __restrict__ w1b, const short* __restrict__ tb,
                                             const float* __restrict__ fc1b, const float* __restrict__ grng,
                                             const float* __restrict__ nx, short* __restrict__ u,
                                             int l, int cbase) {
  __shared__ short As[8192], Bs[8192];
  f32x4 acc[4][4];
  int bid = blockIdx.x;
  int xcd = bid & 7, loc = bid >> 3;
  int nt = (xcd << 5) + (loc >> 3);   // 0..255
  int mt = loc & 7;                   // 0..7
  int m0 = mt * 128, n0 = nt * 128;
  gemm_core_k64<256>(w1b + (size_t)l * 262144, tb + (size_t)cbase * 256, m0, n0, As, Bs, acc);
  const int lane = threadIdx.x & 63, wave = threadIdx.x >> 6;
  const int wr = wave >> 1, wc = wave & 1, lr = lane & 15, kg = lane >> 4;
  int nimg = (cbase + n0) >> 10;
#pragma unroll
  for (int mi = 0; mi < 4; ++mi) {
    int dbase = m0 + wr * 64 + mi * 16 + kg * 4;
    float b0 = fc1b[l * 1024 + dbase + 0], b1 = fc1b[l * 1024 + dbase + 1];
    float b2 = fc1b[l * 1024 + dbase + 2], b3 = fc1b[l * 1024 + dbase + 3];
    float a0 = 1.f + grng[l * 1024 + dbase + 0] * nx[nimg * 1024 + dbase + 0];
    float a1 = 1.f + grng[l * 1024 + dbase + 1] * nx[nimg * 1024 + dbase + 1];
    float a2 = 1.f + grng[l * 1024 + dbase + 2] * nx[nimg * 1024 + dbase + 2];
    float a3 = 1.f + grng[l * 1024 + dbase + 3] * nx[nimg * 1024 + dbase + 3];
#pragma unroll
    for (int ni = 0; ni < 4; ++ni) {
      int pl = n0 + wc * 64 + ni * 16 + lr;
      f32x4 v = acc[mi][ni];
      short4 sv;
      sv.x = f2bf(gelu(v[0] + b0) * a0);
      sv.y = f2bf(gelu(v[1] + b1) * a1);
      sv.z = f2bf(gelu(v[2] + b2) * a2);
      sv.w = f2bf(gelu(v[3] + b3) * a3);
      *(short4*)&u[(size_t)pl * 1024 + dbase] = sv;
    }
  }
}

// ======================= fc2 (128x64 tile, XCD-chunked): hb += u@W2^T + b2 + cvec ========
// 1D grid 1024 = 8 XCD x 64 n-tiles x 2 m-tiles
template <int LAST>
__global__ void __launch_bounds__(256) k_fc2(const short* __restrict__ w2b, const short* __restrict__ u,
                                             const float* __restrict__ fc2b, const float* __restrict__ cvec,
                                             short* __restrict__ hb, short* __restrict__ ht,
                                             int l, int cbase) {
  __shared__ short As[4096], Bs[2048];
  f32x4 acc[4][2];
  int bid = blockIdx.x;
  int xcd = bid & 7, loc = bid >> 3;
  int nt = (xcd << 6) + (loc >> 1);   // 0..511
  int mt = loc & 1;                   // 0..1
  int m0 = mt * 128, n0 = nt * 64;
  gemm_core_n64<1024>(w2b + (size_t)l * 262144, u, m0, n0, As, Bs, acc);
  const int lane = threadIdx.x & 63, wave = threadIdx.x >> 6;
  const int wr = wave >> 1, wc = wave & 1, lr = lane & 15, kg = lane >> 4;
#pragma unroll
  for (int mi = 0; mi < 4; ++mi) {
    int ebase = m0 + wr * 64 + mi * 16 + kg * 4;
    float add0 = fc2b[l * 256 + ebase + 0] + cvec[l * 256 + ebase + 0];
    float add1 = fc2b[l * 256 + ebase + 1] + cvec[l * 256 + ebase + 1];
    float add2 = fc2b[l * 256 + ebase + 2] + cvec[l * 256 + ebase + 2];
    float add3 = fc2b[l * 256 + ebase + 3] + cvec[l * 256 + ebase + 3];
#pragma unroll
    for (int ni = 0; ni < 2; ++ni) {
      int P = cbase + n0 + wc * 32 + ni * 16 + lr;
      int n = P >> 10, p = P & 1023;
      f32x4 v = acc[mi][ni];
      short* hp0 = &hb[((size_t)(n * 256 + ebase) << 10) + p];
      float r0 = v[0] + add0 + bf2f(hp0[0]);
      float r1 = v[1] + add1 + bf2f(hp0[1 << 10]);
      float r2 = v[2] + add2 + bf2f(hp0[2 << 10]);
      float r3 = v[3] + add3 + bf2f(hp0[3 << 10]);
      if (LAST) {
        short* hr = &ht[(size_t)P * 256 + ebase];
        hr[0] = f2bf(r0); hr[1] = f2bf(r1); hr[2] = f2bf(r2); hr[3] = f2bf(r3);
      } else {
        hp0[0] = f2bf(r0); hp0[1 << 10] = f2bf(r1); hp0[2 << 10] = f2bf(r2); hp0[3 << 10] = f2bf(r3);
      }
    }
  }
}

// ======================= pred: MFMA GEMM (32 x 65536 x 256) + fused pixel shuffle ========
__global__ void __launch_bounds__(128) k_pred2(const short* __restrict__ ht, const float* __restrict__ pw,
                                               const float* __restrict__ pb, float* __restrict__ out) {
  __shared__ short Aw[32 * 264];
  __shared__ short Bl[256 * 32];
  int tid = threadIdx.x;
  int n0 = blockIdx.x * 256;
  for (int i = tid; i < 8192; i += 128) {
    int o = i >> 8, e = i & 255;
    Aw[o * 264 + e] = f2bf(pw[i]);
  }
  const int lane = tid & 63, wave = tid >> 6;
  const int lr = lane & 15, kg = lane >> 4;
  const int sr = lane >> 2, sc = (lane & 3) * 8;
  f32x4 acc[2][8];
#pragma unroll
  for (int mi = 0; mi < 2; ++mi)
#pragma unroll
    for (int ni = 0; ni < 8; ++ni) acc[mi][ni] = f32x4{0.f, 0.f, 0.f, 0.f};
  __syncthreads();
  for (int k0 = 0; k0 < 256; k0 += 32) {
#pragma unroll
    for (int j = 0; j < 8; ++j) {
      int rb = wave * 128 + j * 16;
      gload16(ht + (size_t)(n0 + rb + sr) * 256 + k0 + sc, Bl + rb * 32);
    }
    __syncthreads();
    bf16x8 af[2], bfr[8];
#pragma unroll
    for (int mi = 0; mi < 2; ++mi) af[mi] = *(const bf16x8*)&Aw[(mi * 16 + lr) * 264 + k0 + kg * 8];
#pragma unroll
    for (int ni = 0; ni < 8; ++ni) bfr[ni] = *(const bf16x8*)&Bl[(wave * 128 + ni * 16 + lr) * 32 + kg * 8];
#pragma unroll
    for (int mi = 0; mi < 2; ++mi)
#pragma unroll
      for (int ni = 0; ni < 8; ++ni)
        acc[mi][ni] = __builtin_amdgcn_mfma_f32_16x16x32_bf16(af[mi], bfr[ni], acc[mi][ni], 0, 0, 0);
    __syncthreads();
  }
#pragma unroll
  for (int mi = 0; mi < 2; ++mi) {
#pragma unroll
    for (int ni = 0; ni < 8; ++ni) {
      int P = n0 + wave * 128 + ni * 16 + lr;
      int n = P >> 10, p = P & 1023;
      int y = p >> 5, xx = p & 31;
      f32x4 v = acc[mi][ni];
#pragma unroll
      for (int r = 0; r < 4; ++r) {
        int o = mi * 16 + kg * 4 + r;
        int s1 = o >> 3, s2 = (o >> 1) & 3, tt = o & 1;
        size_t oi = (((size_t)n * 128 + y * 4 + s1) * 128 + xx * 4 + s2) * 2 + tt;
        out[oi] = v[r] + pb[o];
      }
    }
  }
}

extern "C" void kernel_launch(void* const* d_in, const int* in_sizes, int n_in,
                              void* d_out, int out_size, void* d_ws, size_t ws_size,
                              hipStream_t stream) {
  const float* x    = (const float*)d_in[0];
  const int*   idx  = (const int*)d_in[1];
  const float* hkw  = (const float*)d_in[2];
  const float* hkb  = (const float*)d_in[3];
  const float* dww  = (const float*)d_in[4];
  const float* dwb  = (const float*)d_in[5];
  const float* lng  = (const float*)d_in[6];
  const float* lnb  = (const float*)d_in[7];
  const float* fc1w = (const float*)d_in[8];
  const float* fc1b = (const float*)d_in[9];
  const float* grng = (const float*)d_in[10];
  const float* grnb = (const float*)d_in[11];
  const float* fc2w = (const float*)d_in[12];
  const float* fc2b = (const float*)d_in[13];
  const float* pw   = (const float*)d_in[14];
  const float* pb   = (const float*)d_in[15];
  float* out = (float*)d_out;

  char* ws = (char*)d_ws;
  short* hb   = (short*)(ws);                            // bf16 residual NCHW
  short* tb   = (short*)(ws + (32ull << 20));            // LN'd NHWC (swizzled); ht last layer
  short* u    = (short*)(ws + (64ull << 20));            // 64MB: 32-image hidden chunk
  short* tc   = (short*)(ws + (64ull << 20));            // overlay (conv->ln only)
  short* Wt   = (short*)(ws + (64ull << 20));            // overlay (prologue only)
  short* xTb  = (short*)(ws + (72ull << 20));            // overlay (prologue only)
  short* w1b  = (short*)(ws + (128ull << 20));
  short* w2b  = (short*)(ws + (130ull << 20));
  float* gx   = (float*)(ws + (132ull << 20));
  float* nx   = (float*)(ws + (132ull << 20) + (1 << 18));
  float* cvec = (float*)(ws + (132ull << 20) + (2 << 18));
  int*   flag = (int*)  (ws + (132ull << 20) + (2 << 18) + 4096);

  k_cvt_w<<<4096, 256, 0, stream>>>(fc1w, fc2w, w1b, w2b);
  k_prep_misc<<<dim3(257, 4), 256, 0, stream>>>(grng, grnb, fc2w, flag, cvec);
  k_prep_xt<<<dim3(32, 8, 4), 256, 0, stream>>>(x, xTb);
  k_prep_wt<<<dim3(8, 8, 64), 256, 0, stream>>>(hkw, idx, Wt);
  k_hypm<<<dim3(8, 2, 64), 256, 0, stream>>>(Wt, xTb, idx, hkb, hb);
  for (int l = 0; l < 4; ++l) {
    k_conv<<<dim3(256, 64), 128, 0, stream>>>(hb, dww, dwb, tc, l);
    k_ln<<<dim3(32, 64), 256, 0, stream>>>(tc, lng, lnb, tb, gx, flag, l);
    k_gx1<<<dim3(512, 8), 256, 0, stream>>>(w1b, tb, fc1b, gx, flag, l);
    k_nx<<<64, 256, 0, stream>>>(gx, nx, flag, l);
    for (int c = 0; c < 2; ++c) {
      int cbase = c * 32768;
      k_fc1<<<2048, 256, 0, stream>>>(w1b, tb, fc1b, grng, nx, u, l, cbase);
      if (l < 3)
        k_fc2<0><<<1024, 256, 0, stream>>>(w2b, u, fc2b, cvec, hb, tb, l, cbase);
      else
        k_fc2<1><<<1024, 256, 0, stream>>>(w2b, u, fc2b, cvec, hb, tb, l, cbase);
    }
  }
  k_pred2<<<256, 128, 0, stream>>>(tb, pw, pb, out);
}

// Round 15
// 822.751 us; speedup vs baseline: 1.3065x; 1.3065x over previous
//
#include <hip/hip_runtime.h>
#include <hip/hip_bf16.h>
#include <math.h>

// B=4, C=16 -> N=64 images; E=256; H=W=32 -> P=1024/img, 65536 total; I=256; HID=1024; L=4
// ws layout (~132.6MB):
//   hb   bf16[64][256][1024]  @0      32MB   residual stream (NCHW, bf16)
//   tb   bf16[65536][256]     @32MB   32MB   LN'd NHWC, SLOT-SWIZZLED (s^=(px&7) per 128B blk);
//                                            final-layer ht (unswizzled) overwrites consumed rows
//   u    bf16[32768][1024]    @64MB   64MB   hidden chunk (32 images, 2 chunks/layer)
//     overlays in u region: tc bf16[64][256][1024]; Wt @64MB; xTb @72MB (prologue)
//   w1b  @128MB 2MB (SLOT-SWIZZLED by d&7); w2b @130MB 2MB (plain); gx @132MB; nx; cvec; flag

typedef __attribute__((ext_vector_type(8))) __bf16 bf16x8;
typedef __attribute__((ext_vector_type(4))) float f32x4;

__device__ __forceinline__ short f2bf(float f) {
  unsigned u = __float_as_uint(f);
  unsigned r = (u + 0x7FFFu + ((u >> 16) & 1u)) >> 16;
  return (short)r;
}
__device__ __forceinline__ float bf2f(short s) {
  return __uint_as_float(((unsigned)(unsigned short)s) << 16);
}
__device__ __forceinline__ int pack2(short a, short b) {
  return (int)(unsigned short)a | ((int)(unsigned short)b << 16);
}
// tanh-approx GELU, sigmoid form, hardware rcp (v_rcp_f32; ~1e-7 rel err)
__device__ __forceinline__ float gelu(float x) {
  float t = __builtin_fmaf(0.0713548162f * x * x, x, 1.59576912f * x);
  return x * __builtin_amdgcn_rcpf(1.f + __expf(-t));
}

__device__ __forceinline__ void gload16(const short* g, short* l) {
  __builtin_amdgcn_global_load_lds(
      (const __attribute__((address_space(1))) void*)(g),
      (__attribute__((address_space(3))) void*)(l), 16, 0, 0);
}

__device__ __forceinline__ float block_sum(float v, float* red) {
#pragma unroll
  for (int o = 32; o > 0; o >>= 1) v += __shfl_down(v, o);
  int lane = threadIdx.x & 63, w = threadIdx.x >> 6;
  int nw = blockDim.x >> 6;
  if (lane == 0) red[w] = v;
  __syncthreads();
  if (threadIdx.x == 0) {
    float s = 0.f;
    for (int i = 0; i < nw; ++i) s += red[i];
    red[0] = s;
  }
  __syncthreads();
  float s = red[0];
  __syncthreads();
  return s;
}

// ======================= MFMA GEMM core (BK=32, linear LDS; m97 structure) ==============
template <int K>
__device__ __forceinline__ void gemm_core(const short* __restrict__ A, const short* __restrict__ Bt,
                                          int m0, int n0, short* As, short* Bs, f32x4 acc[4][4]) {
  const int tid = threadIdx.x;
  const int lane = tid & 63, wave = tid >> 6;
  const int wr = wave >> 1, wc = wave & 1;
  const int lr = lane & 15, kg = lane >> 4;
#pragma unroll
  for (int mi = 0; mi < 4; ++mi)
#pragma unroll
    for (int ni = 0; ni < 4; ++ni) acc[mi][ni] = f32x4{0.f, 0.f, 0.f, 0.f};
  const int sr = lane >> 2, sc = (lane & 3) * 8;
  const int ra0 = wave * 16, ra1 = wave * 16 + 64;
  const short* Ab = A + (size_t)m0 * K;
  const short* Bb = Bt + (size_t)n0 * K;
  for (int k0 = 0; k0 < K; k0 += 32) {
    gload16(Ab + (size_t)(ra0 + sr) * K + k0 + sc, As + ra0 * 32);
    gload16(Ab + (size_t)(ra1 + sr) * K + k0 + sc, As + ra1 * 32);
    gload16(Bb + (size_t)(ra0 + sr) * K + k0 + sc, Bs + ra0 * 32);
    gload16(Bb + (size_t)(ra1 + sr) * K + k0 + sc, Bs + ra1 * 32);
    __syncthreads();
    bf16x8 af[4], bfr[4];
#pragma unroll
    for (int mi = 0; mi < 4; ++mi) af[mi] = *(const bf16x8*)&As[(wr * 64 + mi * 16 + lr) * 32 + kg * 8];
#pragma unroll
    for (int ni = 0; ni < 4; ++ni) bfr[ni] = *(const bf16x8*)&Bs[(wc * 64 + ni * 16 + lr) * 32 + kg * 8];
#pragma unroll
    for (int mi = 0; mi < 4; ++mi)
#pragma unroll
      for (int ni = 0; ni < 4; ++ni)
        acc[mi][ni] = __builtin_amdgcn_mfma_f32_16x16x32_bf16(af[mi], bfr[ni], acc[mi][ni], 0, 0, 0);
    __syncthreads();
  }
}

// ======================= MFMA GEMM core (BK=64, swizzled operands) ======================
// A,Bt pre-swizzled in GLOBAL memory: 16B slot j of each 128B block of row r holds slot j^(r&7).
template <int K>
__device__ __forceinline__ void gemm_core_k64(const short* __restrict__ A, const short* __restrict__ Bt,
                                              int m0, int n0, short* As, short* Bs, f32x4 acc[4][4]) {
  const int tid = threadIdx.x;
  const int lane = tid & 63, wave = tid >> 6;
  const int wr = wave >> 1, wc = wave & 1;
  const int lr = lane & 15, kg = lane >> 4;
#pragma unroll
  for (int mi = 0; mi < 4; ++mi)
#pragma unroll
    for (int ni = 0; ni < 4; ++ni) acc[mi][ni] = f32x4{0.f, 0.f, 0.f, 0.f};
  const int sr = lane >> 3;          // 0..7
  const int sc = (lane & 7) * 8;     // 0..56
  const short* Ab = A + (size_t)m0 * K;
  const short* Bb = Bt + (size_t)n0 * K;
  for (int k0 = 0; k0 < K; k0 += 64) {
#pragma unroll
    for (int j = 0; j < 4; ++j) {
      int r = wave * 8 + j * 32;
      gload16(Ab + (size_t)(r + sr) * K + k0 + sc, As + r * 64);
      gload16(Bb + (size_t)(r + sr) * K + k0 + sc, Bs + r * 64);
    }
    __syncthreads();
#pragma unroll
    for (int ks = 0; ks < 2; ++ks) {
      bf16x8 af[4], bfr[4];
#pragma unroll
      for (int mi = 0; mi < 4; ++mi) {
        int R = wr * 64 + mi * 16 + lr;
        int s = ks * 4 + kg;
        af[mi] = *(const bf16x8*)&As[R * 64 + ((s ^ (R & 7)) << 3)];
      }
#pragma unroll
      for (int ni = 0; ni < 4; ++ni) {
        int R = wc * 64 + ni * 16 + lr;
        int s = ks * 4 + kg;
        bfr[ni] = *(const bf16x8*)&Bs[R * 64 + ((s ^ (R & 7)) << 3)];
      }
#pragma unroll
      for (int mi = 0; mi < 4; ++mi)
#pragma unroll
        for (int ni = 0; ni < 4; ++ni)
          acc[mi][ni] = __builtin_amdgcn_mfma_f32_16x16x32_bf16(af[mi], bfr[ni], acc[mi][ni], 0, 0, 0);
    }
    __syncthreads();
  }
}

// ======================= MFMA GEMM core, 128(m) x 64(n) tile (BK=32, linear) ============
template <int K>
__device__ __forceinline__ void gemm_core_n64(const short* __restrict__ A, const short* __restrict__ Bt,
                                              int m0, int n0, short* As, short* Bs, f32x4 acc[4][2]) {
  const int tid = threadIdx.x;
  const int lane = tid & 63, wave = tid >> 6;
  const int wr = wave >> 1, wc = wave & 1;
  const int lr = lane & 15, kg = lane >> 4;
#pragma unroll
  for (int mi = 0; mi < 4; ++mi)
#pragma unroll
    for (int ni = 0; ni < 2; ++ni) acc[mi][ni] = f32x4{0.f, 0.f, 0.f, 0.f};
  const int sr = lane >> 2, sc = (lane & 3) * 8;
  const int ra0 = wave * 16, ra1 = wave * 16 + 64;
  const short* Ab = A + (size_t)m0 * K;
  const short* Bb = Bt + (size_t)n0 * K;
  for (int k0 = 0; k0 < K; k0 += 32) {
    gload16(Ab + (size_t)(ra0 + sr) * K + k0 + sc, As + ra0 * 32);
    gload16(Ab + (size_t)(ra1 + sr) * K + k0 + sc, As + ra1 * 32);
    gload16(Bb + (size_t)(ra0 + sr) * K + k0 + sc, Bs + ra0 * 32);
    __syncthreads();
    bf16x8 af[4], bfr[2];
#pragma unroll
    for (int mi = 0; mi < 4; ++mi) af[mi] = *(const bf16x8*)&As[(wr * 64 + mi * 16 + lr) * 32 + kg * 8];
#pragma unroll
    for (int ni = 0; ni < 2; ++ni) bfr[ni] = *(const bf16x8*)&Bs[(wc * 32 + ni * 16 + lr) * 32 + kg * 8];
#pragma unroll
    for (int mi = 0; mi < 4; ++mi)
#pragma unroll
      for (int ni = 0; ni < 2; ++ni)
        acc[mi][ni] = __builtin_amdgcn_mfma_f32_16x16x32_bf16(af[mi], bfr[ni], acc[mi][ni], 0, 0, 0);
    __syncthreads();
  }
}

// ======================= prep kernels =======================
// w1b stored SLOT-SWIZZLED: 16B slot j within each 64-short block moves to j ^ (d&7).
__global__ void k_cvt_w(const float* __restrict__ fc1w, const float* __restrict__ fc2w,
                        short* __restrict__ w1b, short* __restrict__ w2b) {
  int i = blockIdx.x * 256 + threadIdx.x;  // 4*262144
  int d7 = (i >> 8) & 7;
  int e = i & 255;
  int es = (e & 0xC0) | (((((e >> 3) & 7) ^ d7)) << 3) | (e & 7);
  w1b[(i & ~255) | es] = f2bf(fc1w[i]);
  w2b[i] = f2bf(fc2w[i]);
}

// x [4][256 i][1024 p] f32 -> xTb [4][1024 p][256 i] bf16
__global__ void k_prep_xt(const float* __restrict__ x, short* __restrict__ xTb) {
  __shared__ float tile[32][33];
  int tx = threadIdx.x & 31, ty = threadIdx.x >> 5;
  int p0 = blockIdx.x * 32, i0 = blockIdx.y * 32, b = blockIdx.z;
#pragma unroll
  for (int r = 0; r < 4; ++r) {
    int i = ty + r * 8;
    tile[i][tx] = x[((size_t)b * 256 + i0 + i) * 1024 + p0 + tx];
  }
  __syncthreads();
#pragma unroll
  for (int r = 0; r < 4; ++r) {
    int p = ty + r * 8;
    xTb[((size_t)b * 1024 + p0 + p) * 256 + i0 + tx] = f2bf(tile[tx][p]);
  }
}

// hk_w gather+transpose: Wt[n][e][i] bf16 = hkw[idx[n]][i][e]
__global__ void k_prep_wt(const float* __restrict__ hkw, const int* __restrict__ idx,
                          short* __restrict__ Wt) {
  __shared__ float tile[32][33];
  int tx = threadIdx.x & 31, ty = threadIdx.x >> 5;
  int e0 = blockIdx.x * 32, i0 = blockIdx.y * 32, n = blockIdx.z;
  int ch = idx[n];
#pragma unroll
  for (int r = 0; r < 4; ++r) {
    int i = ty + r * 8;
    tile[i][tx] = hkw[(size_t)ch * 65536 + (size_t)(i0 + i) * 256 + e0 + tx];
  }
  __syncthreads();
#pragma unroll
  for (int r = 0; r < 4; ++r) {
    int e = ty + r * 8;
    Wt[((size_t)n * 256 + e0 + e) * 256 + i0 + tx] = f2bf(tile[tx][e]);
  }
}

// flag[l] = any(grn_g != 0); cvec[l][e] = sum_d fc2_w[l][e][d]*grn_b[l][d]
__global__ void k_prep_misc(const float* __restrict__ grng, const float* __restrict__ grnb,
                            const float* __restrict__ fc2w, int* __restrict__ flag,
                            float* __restrict__ cvec) {
  __shared__ float red[8];
  int l = blockIdx.y;
  if (blockIdx.x == 0) {
    float any = 0.f;
    for (int d = threadIdx.x; d < 1024; d += 256)
      any += (grng[l * 1024 + d] != 0.f) ? 1.f : 0.f;
    float tot = block_sum(any, red);
    if (threadIdx.x == 0) flag[l] = (tot > 0.f) ? 1 : 0;
  } else {
    int e = blockIdx.x - 1;
    float s = 0.f;
    for (int d = threadIdx.x; d < 1024; d += 256)
      s += fc2w[((size_t)(l * 256 + e) << 10) + d] * grnb[l * 1024 + d];
    float tot = block_sum(s, red);
    if (threadIdx.x == 0) cvec[l * 256 + e] = tot;
  }
}

// ======================= hyper GEMM: hb[n][e][p] = Wt[n]@xTb[b] + hkb (bf16 out) =========
__global__ void __launch_bounds__(256) k_hypm(const short* __restrict__ Wt, const short* __restrict__ xTb,
                                              const int* __restrict__ idx, const float* __restrict__ hkb,
                                              short* __restrict__ hb) {
  __shared__ short As[4096], Bs[4096];
  f32x4 acc[4][4];
  int n = blockIdx.z;
  int m0 = blockIdx.y * 128, n0 = blockIdx.x * 128;
  gemm_core<256>(Wt + (size_t)n * 65536, xTb + (size_t)(n >> 4) * 262144, m0, n0, As, Bs, acc);
  int ch = idx[n];
  const int lane = threadIdx.x & 63, wave = threadIdx.x >> 6;
  const int wr = wave >> 1, wc = wave & 1, lr = lane & 15, kg = lane >> 4;
#pragma unroll
  for (int mi = 0; mi < 4; ++mi) {
    int ebase = m0 + wr * 64 + mi * 16 + kg * 4;
#pragma unroll
    for (int ni = 0; ni < 4; ++ni) {
      int p = n0 + wc * 64 + ni * 16 + lr;
      f32x4 v = acc[mi][ni];
#pragma unroll
      for (int r = 0; r < 4; ++r)
        hb[((size_t)(n * 256 + ebase + r) << 10) + p] = f2bf(v[r] + hkb[ch * 256 + ebase + r]);
    }
  }
}

// ======================= depthwise 7x7 conv: LDS-staged, NCHW bf16 -> NCHW bf16 (tc) =====
// Proven structure: 256 thr, scalar b32 taps (2-way aliasing = free), 0 conflicts, ~45us.
__global__ void __launch_bounds__(256) k_conv(const short* __restrict__ hb, const float* __restrict__ dww,
                                              const float* __restrict__ dwb, short* __restrict__ tc, int l) {
  __shared__ float sm[38][40];
  int e = blockIdx.x, n = blockIdx.y;
  const short* plane = hb + (((size_t)(n * 256 + e)) << 10);
  const float* wv = dww + ((size_t)(l * 256 + e)) * 49;
  float w[49];
#pragma unroll
  for (int i = 0; i < 49; ++i) w[i] = wv[i];  // uniform address -> scalar loads
  int tid = threadIdx.x;
  for (int i = tid; i < 38 * 40; i += 256) ((float*)sm)[i] = 0.f;
  __syncthreads();
  {
    const int* plane32 = (const int*)plane;
    for (int i = tid; i < 512; i += 256) {
      int v = plane32[i];
      int p = i * 2;
      int iy = p >> 5, ix = p & 31;
      sm[iy + 3][ix + 3] = bf2f((short)(v & 0xffff));
      sm[iy + 3][ix + 4] = bf2f((short)(v >> 16));
    }
  }
  __syncthreads();
  int x = tid & 31, y0 = (tid >> 5) * 4;
  float bias = dwb[l * 256 + e];
  float acc0 = bias, acc1 = bias, acc2 = bias, acc3 = bias;
#pragma unroll
  for (int r = 0; r < 10; ++r) {
#pragma unroll
    for (int c = 0; c < 7; ++c) {
      float v = sm[y0 + r][x + c];
      if (r <= 6)           acc0 += v * w[r * 7 + c];
      if (r >= 1 && r <= 7) acc1 += v * w[(r - 1) * 7 + c];
      if (r >= 2 && r <= 8) acc2 += v * w[(r - 2) * 7 + c];
      if (r >= 3)           acc3 += v * w[(r - 3) * 7 + c];
    }
  }
  short* outp = tc + (((size_t)(n * 256 + e)) << 10) + y0 * 32 + x;
  outp[0]  = f2bf(acc0);
  outp[32] = f2bf(acc1);
  outp[64] = f2bf(acc2);
  outp[96] = f2bf(acc3);
}

// ======================= LayerNorm + NCHW->NHWC transpose (tc -> tb, SWIZZLED store) =====
__global__ void __launch_bounds__(256) k_ln(const short* __restrict__ tc, const float* __restrict__ lng,
                                            const float* __restrict__ lnb, short* __restrict__ tb,
                                            float* __restrict__ gx, const int* __restrict__ flag, int l) {
  __shared__ float smT[32][261];
  __shared__ float muS[32], rsS[32];
  int n = blockIdx.y, p0 = blockIdx.x * 32;
  int tid = threadIdx.x;
  if (blockIdx.x == 0 && flag[l] != 0) {
#pragma unroll
    for (int r = 0; r < 4; ++r) gx[n * 1024 + r * 256 + tid] = 0.f;
  }
  const short* base = tc + ((size_t)n << 18) + p0;
  for (int i = tid; i < 8192; i += 256) {
    int e = i >> 5, p = i & 31;
    smT[p][e] = bf2f(base[(e << 10) + p]);
  }
  __syncthreads();
  {
    int j = tid & 7, p = tid >> 3;
    float s = 0.f, q = 0.f;
#pragma unroll
    for (int i = 0; i < 32; ++i) {
      float v = smT[p][j + i * 8];
      s += v; q += v * v;
    }
    s += __shfl_xor(s, 1); q += __shfl_xor(q, 1);
    s += __shfl_xor(s, 2); q += __shfl_xor(q, 2);
    s += __shfl_xor(s, 4); q += __shfl_xor(q, 4);
    if (j == 0) {
      float mu = s * (1.f / 256.f);
      float var = q * (1.f / 256.f) - mu * mu;
      muS[p] = mu;
      rsS[p] = rsqrtf(fmaxf(var, 0.f) + 1e-5f);
    }
  }
  __syncthreads();
  for (int i = tid; i < 8192; i += 256) {
    int p = i >> 8, e = i & 255;
    int px = n * 1024 + p0 + p;
    float v = (smT[p][e] - muS[p]) * rsS[p] * lng[l * 256 + e] + lnb[l * 256 + e];
    int es = (e & 0xC0) | ((((e >> 3) & 7) ^ (px & 7)) << 3) | (e & 7);
    tb[((size_t)px) * 256 + es] = f2bf(v);
  }
}

// ======================= GRN general path (flag-gated; no-op for this data) ==============
__global__ void __launch_bounds__(256) k_gx1(const short* __restrict__ w1b, const short* __restrict__ tb,
                                             const float* __restrict__ fc1b, float* __restrict__ gx,
                                             const int* __restrict__ flag, int l) {
  if (flag[l] == 0) return;
  __shared__ short As[8192], Bs[8192];
  f32x4 acc[4][4];
  int m0 = blockIdx.y * 128, n0 = blockIdx.x * 128;
  gemm_core_k64<256>(w1b + (size_t)l * 262144, tb, m0, n0, As, Bs, acc);
  const int lane = threadIdx.x & 63, wave = threadIdx.x >> 6;
  const int wr = wave >> 1, kg = lane >> 4;
  int n = (n0 >> 10);
#pragma unroll
  for (int mi = 0; mi < 4; ++mi) {
    int dbase = m0 + wr * 64 + mi * 16 + kg * 4;
#pragma unroll
    for (int ni = 0; ni < 4; ++ni) {
      f32x4 v = acc[mi][ni];
#pragma unroll
      for (int r = 0; r < 4; ++r) {
        float g = gelu(v[r] + fc1b[l * 1024 + dbase + r]);
        atomicAdd(&gx[n * 1024 + dbase + r], g * g);
      }
    }
  }
}

__global__ void k_nx(const float* __restrict__ gx, float* __restrict__ nx,
                     const int* __restrict__ flag, int l) {
  int n = blockIdx.x, tid = threadIdx.x;
  if (flag[l] == 0) {
    for (int d = tid; d < 1024; d += 256) nx[n * 1024 + d] = 0.f;
    return;
  }
  __shared__ float red[8];
  __shared__ float sv[1024];
  float s = 0.f;
  for (int d = tid; d < 1024; d += 256) {
    float v = sqrtf(gx[n * 1024 + d]);
    sv[d] = v; s += v;
  }
  float tot = block_sum(s, red);
  float mean = tot * (1.f / 1024.f);
  for (int d = tid; d < 1024; d += 256) nx[n * 1024 + d] = sv[d] / (mean + 1e-6f);
}

// ======================= fc1 (BK=64 swizzled core): u = gelu(tb@W1^T+b1)*(1+g*nx) ========
// 1D grid 2048 = 8 XCD x 32 n-tiles x 8 m-tiles
__global__ void __launch_bounds__(256) k_fc1(const short* __restrict__ w1b, const short* __restrict__ tb,
                                             const float* __restrict__ fc1b, const float* __restrict__ grng,
                                             const float* __restrict__ nx, short* __restrict__ u,
                                             int l, int cbase) {
  __shared__ short As[8192], Bs[8192];
  f32x4 acc[4][4];
  int bid = blockIdx.x;
  int xcd = bid & 7, loc = bid >> 3;
  int nt = (xcd << 5) + (loc >> 3);   // 0..255
  int mt = loc & 7;                   // 0..7
  int m0 = mt * 128, n0 = nt * 128;
  gemm_core_k64<256>(w1b + (size_t)l * 262144, tb + (size_t)cbase * 256, m0, n0, As, Bs, acc);
  const int lane = threadIdx.x & 63, wave = threadIdx.x >> 6;
  const int wr = wave >> 1, wc = wave & 1, lr = lane & 15, kg = lane >> 4;
  int nimg = (cbase + n0) >> 10;
#pragma unroll
  for (int mi = 0; mi < 4; ++mi) {
    int dbase = m0 + wr * 64 + mi * 16 + kg * 4;
    float b0 = fc1b[l * 1024 + dbase + 0], b1 = fc1b[l * 1024 + dbase + 1];
    float b2 = fc1b[l * 1024 + dbase + 2], b3 = fc1b[l * 1024 + dbase + 3];
    float a0 = 1.f + grng[l * 1024 + dbase + 0] * nx[nimg * 1024 + dbase + 0];
    float a1 = 1.f + grng[l * 1024 + dbase + 1] * nx[nimg * 1024 + dbase + 1];
    float a2 = 1.f + grng[l * 1024 + dbase + 2] * nx[nimg * 1024 + dbase + 2];
    float a3 = 1.f + grng[l * 1024 + dbase + 3] * nx[nimg * 1024 + dbase + 3];
#pragma unroll
    for (int ni = 0; ni < 4; ++ni) {
      int pl = n0 + wc * 64 + ni * 16 + lr;
      f32x4 v = acc[mi][ni];
      short4 sv;
      sv.x = f2bf(gelu(v[0] + b0) * a0);
      sv.y = f2bf(gelu(v[1] + b1) * a1);
      sv.z = f2bf(gelu(v[2] + b2) * a2);
      sv.w = f2bf(gelu(v[3] + b3) * a3);
      *(short4*)&u[(size_t)pl * 1024 + dbase] = sv;
    }
  }
}

// ======================= fc2 (128x64 tile, XCD-chunked): hb += u@W2^T + b2 + cvec ========
// 1D grid 1024 = 8 XCD x 64 n-tiles x 2 m-tiles
template <int LAST>
__global__ void __launch_bounds__(256) k_fc2(const short* __restrict__ w2b, const short* __restrict__ u,
                                             const float* __restrict__ fc2b, const float* __restrict__ cvec,
                                             short* __restrict__ hb, short* __restrict__ ht,
                                             int l, int cbase) {
  __shared__ short As[4096], Bs[2048];
  f32x4 acc[4][2];
  int bid = blockIdx.x;
  int xcd = bid & 7, loc = bid >> 3;
  int nt = (xcd << 6) + (loc >> 1);   // 0..511
  int mt = loc & 1;                   // 0..1
  int m0 = mt * 128, n0 = nt * 64;
  gemm_core_n64<1024>(w2b + (size_t)l * 262144, u, m0, n0, As, Bs, acc);
  const int lane = threadIdx.x & 63, wave = threadIdx.x >> 6;
  const int wr = wave >> 1, wc = wave & 1, lr = lane & 15, kg = lane >> 4;
#pragma unroll
  for (int mi = 0; mi < 4; ++mi) {
    int ebase = m0 + wr * 64 + mi * 16 + kg * 4;
    float add0 = fc2b[l * 256 + ebase + 0] + cvec[l * 256 + ebase + 0];
    float add1 = fc2b[l * 256 + ebase + 1] + cvec[l * 256 + ebase + 1];
    float add2 = fc2b[l * 256 + ebase + 2] + cvec[l * 256 + ebase + 2];
    float add3 = fc2b[l * 256 + ebase + 3] + cvec[l * 256 + ebase + 3];
#pragma unroll
    for (int ni = 0; ni < 2; ++ni) {
      int P = cbase + n0 + wc * 32 + ni * 16 + lr;
      int n = P >> 10, p = P & 1023;
      f32x4 v = acc[mi][ni];
      short* hp0 = &hb[((size_t)(n * 256 + ebase) << 10) + p];
      float r0 = v[0] + add0 + bf2f(hp0[0]);
      float r1 = v[1] + add1 + bf2f(hp0[1 << 10]);
      float r2 = v[2] + add2 + bf2f(hp0[2 << 10]);
      float r3 = v[3] + add3 + bf2f(hp0[3 << 10]);
      if (LAST) {
        short* hr = &ht[(size_t)P * 256 + ebase];
        hr[0] = f2bf(r0); hr[1] = f2bf(r1); hr[2] = f2bf(r2); hr[3] = f2bf(r3);
      } else {
        hp0[0] = f2bf(r0); hp0[1 << 10] = f2bf(r1); hp0[2 << 10] = f2bf(r2); hp0[3 << 10] = f2bf(r3);
      }
    }
  }
}

// ======================= pred: MFMA GEMM (32 x 65536 x 256) + fused pixel shuffle ========
__global__ void __launch_bounds__(128) k_pred2(const short* __restrict__ ht, const float* __restrict__ pw,
                                               const float* __restrict__ pb, float* __restrict__ out) {
  __shared__ short Aw[32 * 264];
  __shared__ short Bl[256 * 32];
  int tid = threadIdx.x;
  int n0 = blockIdx.x * 256;
  for (int i = tid; i < 8192; i += 128) {
    int o = i >> 8, e = i & 255;
    Aw[o * 264 + e] = f2bf(pw[i]);
  }
  const int lane = tid & 63, wave = tid >> 6;
  const int lr = lane & 15, kg = lane >> 4;
  const int sr = lane >> 2, sc = (lane & 3) * 8;
  f32x4 acc[2][8];
#pragma unroll
  for (int mi = 0; mi < 2; ++mi)
#pragma unroll
    for (int ni = 0; ni < 8; ++ni) acc[mi][ni] = f32x4{0.f, 0.f, 0.f, 0.f};
  __syncthreads();
  for (int k0 = 0; k0 < 256; k0 += 32) {
#pragma unroll
    for (int j = 0; j < 8; ++j) {
      int rb = wave * 128 + j * 16;
      gload16(ht + (size_t)(n0 + rb + sr) * 256 + k0 + sc, Bl + rb * 32);
    }
    __syncthreads();
    bf16x8 af[2], bfr[8];
#pragma unroll
    for (int mi = 0; mi < 2; ++mi) af[mi] = *(const bf16x8*)&Aw[(mi * 16 + lr) * 264 + k0 + kg * 8];
#pragma unroll
    for (int ni = 0; ni < 8; ++ni) bfr[ni] = *(const bf16x8*)&Bl[(wave * 128 + ni * 16 + lr) * 32 + kg * 8];
#pragma unroll
    for (int mi = 0; mi < 2; ++mi)
#pragma unroll
      for (int ni = 0; ni < 8; ++ni)
        acc[mi][ni] = __builtin_amdgcn_mfma_f32_16x16x32_bf16(af[mi], bfr[ni], acc[mi][ni], 0, 0, 0);
    __syncthreads();
  }
#pragma unroll
  for (int mi = 0; mi < 2; ++mi) {
#pragma unroll
    for (int ni = 0; ni < 8; ++ni) {
      int P = n0 + wave * 128 + ni * 16 + lr;
      int n = P >> 10, p = P & 1023;
      int y = p >> 5, xx = p & 31;
      f32x4 v = acc[mi][ni];
#pragma unroll
      for (int r = 0; r < 4; ++r) {
        int o = mi * 16 + kg * 4 + r;
        int s1 = o >> 3, s2 = (o >> 1) & 3, tt = o & 1;
        size_t oi = (((size_t)n * 128 + y * 4 + s1) * 128 + xx * 4 + s2) * 2 + tt;
        out[oi] = v[r] + pb[o];
      }
    }
  }
}

extern "C" void kernel_launch(void* const* d_in, const int* in_sizes, int n_in,
                              void* d_out, int out_size, void* d_ws, size_t ws_size,
                              hipStream_t stream) {
  const float* x    = (const float*)d_in[0];
  const int*   idx  = (const int*)d_in[1];
  const float* hkw  = (const float*)d_in[2];
  const float* hkb  = (const float*)d_in[3];
  const float* dww  = (const float*)d_in[4];
  const float* dwb  = (const float*)d_in[5];
  const float* lng  = (const float*)d_in[6];
  const float* lnb  = (const float*)d_in[7];
  const float* fc1w = (const float*)d_in[8];
  const float* fc1b = (const float*)d_in[9];
  const float* grng = (const float*)d_in[10];
  const float* grnb = (const float*)d_in[11];
  const float* fc2w = (const float*)d_in[12];
  const float* fc2b = (const float*)d_in[13];
  const float* pw   = (const float*)d_in[14];
  const float* pb   = (const float*)d_in[15];
  float* out = (float*)d_out;

  char* ws = (char*)d_ws;
  short* hb   = (short*)(ws);                            // bf16 residual NCHW
  short* tb   = (short*)(ws + (32ull << 20));            // LN'd NHWC (swizzled); ht last layer
  short* u    = (short*)(ws + (64ull << 20));            // 64MB: 32-image hidden chunk
  short* tc   = (short*)(ws + (64ull << 20));            // overlay (conv->ln only)
  short* Wt   = (short*)(ws + (64ull << 20));            // overlay (prologue only)
  short* xTb  = (short*)(ws + (72ull << 20));            // overlay (prologue only)
  short* w1b  = (short*)(ws + (128ull << 20));
  short* w2b  = (short*)(ws + (130ull << 20));
  float* gx   = (float*)(ws + (132ull << 20));
  float* nx   = (float*)(ws + (132ull << 20) + (1 << 18));
  float* cvec = (float*)(ws + (132ull << 20) + (2 << 18));
  int*   flag = (int*)  (ws + (132ull << 20) + (2 << 18) + 4096);

  k_cvt_w<<<4096, 256, 0, stream>>>(fc1w, fc2w, w1b, w2b);
  k_prep_misc<<<dim3(257, 4), 256, 0, stream>>>(grng, grnb, fc2w, flag, cvec);
  k_prep_xt<<<dim3(32, 8, 4), 256, 0, stream>>>(x, xTb);
  k_prep_wt<<<dim3(8, 8, 64), 256, 0, stream>>>(hkw, idx, Wt);
  k_hypm<<<dim3(8, 2, 64), 256, 0, stream>>>(Wt, xTb, idx, hkb, hb);
  for (int l = 0; l < 4; ++l) {
    k_conv<<<dim3(256, 64), 256, 0, stream>>>(hb, dww, dwb, tc, l);
    k_ln<<<dim3(32, 64), 256, 0, stream>>>(tc, lng, lnb, tb, gx, flag, l);
    k_gx1<<<dim3(512, 8), 256, 0, stream>>>(w1b, tb, fc1b, gx, flag, l);
    k_nx<<<64, 256, 0, stream>>>(gx, nx, flag, l);
    for (int c = 0; c < 2; ++c) {
      int cbase = c * 32768;
      k_fc1<<<2048, 256, 0, stream>>>(w1b, tb, fc1b, grng, nx, u, l, cbase);
      if (l < 3)
        k_fc2<0><<<1024, 256, 0, stream>>>(w2b, u, fc2b, cvec, hb, tb, l, cbase);
      else
        k_fc2<1><<<1024, 256, 0, stream>>>(w2b, u, fc2b, cvec, hb, tb, l, cbase);
    }
  }
  k_pred2<<<256, 128, 0, stream>>>(tb, pw, pb, out);
}

// Round 16
// 811.194 us; speedup vs baseline: 1.3251x; 1.0142x over previous
//
#include <hip/hip_runtime.h>
#include <hip/hip_bf16.h>
#include <math.h>

// B=4, C=16 -> N=64 images; E=256; H=W=32 -> P=1024/img, 65536 total; I=256; HID=1024; L=4
// ws layout (~132.6MB):
//   hb   bf16[64][256][1024]  @0      32MB   residual stream (NCHW, bf16)
//   tb   bf16[65536][256]     @32MB   32MB   LN'd NHWC, SLOT-SWIZZLED (s^=(px&7) per 128B blk);
//                                            final-layer ht (unswizzled) overwrites consumed rows
//   u    bf16[32768][1024]    @64MB   64MB   hidden chunk (32 images, 2 chunks/layer)
//     overlays in u region: tc bf16[64][256][1024]; Wt @64MB; xTb @72MB (prologue)
//   w1b  @128MB 2MB (SLOT-SWIZZLED by d&7); w2b @130MB 2MB (plain); gx @132MB; nx; cvec; flag

typedef __attribute__((ext_vector_type(8))) __bf16 bf16x8;
typedef __attribute__((ext_vector_type(4))) float f32x4;

__device__ __forceinline__ short f2bf(float f) {
  unsigned u = __float_as_uint(f);
  unsigned r = (u + 0x7FFFu + ((u >> 16) & 1u)) >> 16;
  return (short)r;
}
__device__ __forceinline__ float bf2f(short s) {
  return __uint_as_float(((unsigned)(unsigned short)s) << 16);
}
__device__ __forceinline__ int pack2(short a, short b) {
  return (int)(unsigned short)a | ((int)(unsigned short)b << 16);
}
// tanh-approx GELU, sigmoid form, hardware rcp (v_rcp_f32; ~1e-7 rel err)
__device__ __forceinline__ float gelu(float x) {
  float t = __builtin_fmaf(0.0713548162f * x * x, x, 1.59576912f * x);
  return x * __builtin_amdgcn_rcpf(1.f + __expf(-t));
}

__device__ __forceinline__ void gload16(const short* g, short* l) {
  __builtin_amdgcn_global_load_lds(
      (const __attribute__((address_space(1))) void*)(g),
      (__attribute__((address_space(3))) void*)(l), 16, 0, 0);
}

__device__ __forceinline__ float block_sum(float v, float* red) {
#pragma unroll
  for (int o = 32; o > 0; o >>= 1) v += __shfl_down(v, o);
  int lane = threadIdx.x & 63, w = threadIdx.x >> 6;
  int nw = blockDim.x >> 6;
  if (lane == 0) red[w] = v;
  __syncthreads();
  if (threadIdx.x == 0) {
    float s = 0.f;
    for (int i = 0; i < nw; ++i) s += red[i];
    red[0] = s;
  }
  __syncthreads();
  float s = red[0];
  __syncthreads();
  return s;
}

// ======================= MFMA GEMM core (BK=32, linear LDS; m97 structure) ==============
template <int K>
__device__ __forceinline__ void gemm_core(const short* __restrict__ A, const short* __restrict__ Bt,
                                          int m0, int n0, short* As, short* Bs, f32x4 acc[4][4]) {
  const int tid = threadIdx.x;
  const int lane = tid & 63, wave = tid >> 6;
  const int wr = wave >> 1, wc = wave & 1;
  const int lr = lane & 15, kg = lane >> 4;
#pragma unroll
  for (int mi = 0; mi < 4; ++mi)
#pragma unroll
    for (int ni = 0; ni < 4; ++ni) acc[mi][ni] = f32x4{0.f, 0.f, 0.f, 0.f};
  const int sr = lane >> 2, sc = (lane & 3) * 8;
  const int ra0 = wave * 16, ra1 = wave * 16 + 64;
  const short* Ab = A + (size_t)m0 * K;
  const short* Bb = Bt + (size_t)n0 * K;
  for (int k0 = 0; k0 < K; k0 += 32) {
    gload16(Ab + (size_t)(ra0 + sr) * K + k0 + sc, As + ra0 * 32);
    gload16(Ab + (size_t)(ra1 + sr) * K + k0 + sc, As + ra1 * 32);
    gload16(Bb + (size_t)(ra0 + sr) * K + k0 + sc, Bs + ra0 * 32);
    gload16(Bb + (size_t)(ra1 + sr) * K + k0 + sc, Bs + ra1 * 32);
    __syncthreads();
    bf16x8 af[4], bfr[4];
#pragma unroll
    for (int mi = 0; mi < 4; ++mi) af[mi] = *(const bf16x8*)&As[(wr * 64 + mi * 16 + lr) * 32 + kg * 8];
#pragma unroll
    for (int ni = 0; ni < 4; ++ni) bfr[ni] = *(const bf16x8*)&Bs[(wc * 64 + ni * 16 + lr) * 32 + kg * 8];
#pragma unroll
    for (int mi = 0; mi < 4; ++mi)
#pragma unroll
      for (int ni = 0; ni < 4; ++ni)
        acc[mi][ni] = __builtin_amdgcn_mfma_f32_16x16x32_bf16(af[mi], bfr[ni], acc[mi][ni], 0, 0, 0);
    __syncthreads();
  }
}

// ======================= MFMA GEMM core (BK=64, swizzled operands) ======================
// A,Bt pre-swizzled in GLOBAL memory: 16B slot j of each 128B block of row r holds slot j^(r&7).
template <int K>
__device__ __forceinline__ void gemm_core_k64(const short* __restrict__ A, const short* __restrict__ Bt,
                                              int m0, int n0, short* As, short* Bs, f32x4 acc[4][4]) {
  const int tid = threadIdx.x;
  const int lane = tid & 63, wave = tid >> 6;
  const int wr = wave >> 1, wc = wave & 1;
  const int lr = lane & 15, kg = lane >> 4;
#pragma unroll
  for (int mi = 0; mi < 4; ++mi)
#pragma unroll
    for (int ni = 0; ni < 4; ++ni) acc[mi][ni] = f32x4{0.f, 0.f, 0.f, 0.f};
  const int sr = lane >> 3;          // 0..7
  const int sc = (lane & 7) * 8;     // 0..56
  const short* Ab = A + (size_t)m0 * K;
  const short* Bb = Bt + (size_t)n0 * K;
  for (int k0 = 0; k0 < K; k0 += 64) {
#pragma unroll
    for (int j = 0; j < 4; ++j) {
      int r = wave * 8 + j * 32;
      gload16(Ab + (size_t)(r + sr) * K + k0 + sc, As + r * 64);
      gload16(Bb + (size_t)(r + sr) * K + k0 + sc, Bs + r * 64);
    }
    __syncthreads();
#pragma unroll
    for (int ks = 0; ks < 2; ++ks) {
      bf16x8 af[4], bfr[4];
#pragma unroll
      for (int mi = 0; mi < 4; ++mi) {
        int R = wr * 64 + mi * 16 + lr;
        int s = ks * 4 + kg;
        af[mi] = *(const bf16x8*)&As[R * 64 + ((s ^ (R & 7)) << 3)];
      }
#pragma unroll
      for (int ni = 0; ni < 4; ++ni) {
        int R = wc * 64 + ni * 16 + lr;
        int s = ks * 4 + kg;
        bfr[ni] = *(const bf16x8*)&Bs[R * 64 + ((s ^ (R & 7)) << 3)];
      }
#pragma unroll
      for (int mi = 0; mi < 4; ++mi)
#pragma unroll
        for (int ni = 0; ni < 4; ++ni)
          acc[mi][ni] = __builtin_amdgcn_mfma_f32_16x16x32_bf16(af[mi], bfr[ni], acc[mi][ni], 0, 0, 0);
    }
    __syncthreads();
  }
}

// ======================= MFMA GEMM core, 128(m) x 64(n) tile (BK=32, linear) ============
template <int K>
__device__ __forceinline__ void gemm_core_n64(const short* __restrict__ A, const short* __restrict__ Bt,
                                              int m0, int n0, short* As, short* Bs, f32x4 acc[4][2]) {
  const int tid = threadIdx.x;
  const int lane = tid & 63, wave = tid >> 6;
  const int wr = wave >> 1, wc = wave & 1;
  const int lr = lane & 15, kg = lane >> 4;
#pragma unroll
  for (int mi = 0; mi < 4; ++mi)
#pragma unroll
    for (int ni = 0; ni < 2; ++ni) acc[mi][ni] = f32x4{0.f, 0.f, 0.f, 0.f};
  const int sr = lane >> 2, sc = (lane & 3) * 8;
  const int ra0 = wave * 16, ra1 = wave * 16 + 64;
  const short* Ab = A + (size_t)m0 * K;
  const short* Bb = Bt + (size_t)n0 * K;
  for (int k0 = 0; k0 < K; k0 += 32) {
    gload16(Ab + (size_t)(ra0 + sr) * K + k0 + sc, As + ra0 * 32);
    gload16(Ab + (size_t)(ra1 + sr) * K + k0 + sc, As + ra1 * 32);
    gload16(Bb + (size_t)(ra0 + sr) * K + k0 + sc, Bs + ra0 * 32);
    __syncthreads();
    bf16x8 af[4], bfr[2];
#pragma unroll
    for (int mi = 0; mi < 4; ++mi) af[mi] = *(const bf16x8*)&As[(wr * 64 + mi * 16 + lr) * 32 + kg * 8];
#pragma unroll
    for (int ni = 0; ni < 2; ++ni) bfr[ni] = *(const bf16x8*)&Bs[(wc * 32 + ni * 16 + lr) * 32 + kg * 8];
#pragma unroll
    for (int mi = 0; mi < 4; ++mi)
#pragma unroll
      for (int ni = 0; ni < 2; ++ni)
        acc[mi][ni] = __builtin_amdgcn_mfma_f32_16x16x32_bf16(af[mi], bfr[ni], acc[mi][ni], 0, 0, 0);
    __syncthreads();
  }
}

// ======================= prep kernels =======================
// w1b stored SLOT-SWIZZLED: 16B slot j within each 64-short block moves to j ^ (d&7).
__global__ void k_cvt_w(const float* __restrict__ fc1w, const float* __restrict__ fc2w,
                        short* __restrict__ w1b, short* __restrict__ w2b) {
  int i = blockIdx.x * 256 + threadIdx.x;  // 4*262144
  int d7 = (i >> 8) & 7;
  int e = i & 255;
  int es = (e & 0xC0) | (((((e >> 3) & 7) ^ d7)) << 3) | (e & 7);
  w1b[(i & ~255) | es] = f2bf(fc1w[i]);
  w2b[i] = f2bf(fc2w[i]);
}

// x [4][256 i][1024 p] f32 -> xTb [4][1024 p][256 i] bf16
__global__ void k_prep_xt(const float* __restrict__ x, short* __restrict__ xTb) {
  __shared__ float tile[32][33];
  int tx = threadIdx.x & 31, ty = threadIdx.x >> 5;
  int p0 = blockIdx.x * 32, i0 = blockIdx.y * 32, b = blockIdx.z;
#pragma unroll
  for (int r = 0; r < 4; ++r) {
    int i = ty + r * 8;
    tile[i][tx] = x[((size_t)b * 256 + i0 + i) * 1024 + p0 + tx];
  }
  __syncthreads();
#pragma unroll
  for (int r = 0; r < 4; ++r) {
    int p = ty + r * 8;
    xTb[((size_t)b * 1024 + p0 + p) * 256 + i0 + tx] = f2bf(tile[tx][p]);
  }
}

// hk_w gather+transpose: Wt[n][e][i] bf16 = hkw[idx[n]][i][e]
__global__ void k_prep_wt(const float* __restrict__ hkw, const int* __restrict__ idx,
                          short* __restrict__ Wt) {
  __shared__ float tile[32][33];
  int tx = threadIdx.x & 31, ty = threadIdx.x >> 5;
  int e0 = blockIdx.x * 32, i0 = blockIdx.y * 32, n = blockIdx.z;
  int ch = idx[n];
#pragma unroll
  for (int r = 0; r < 4; ++r) {
    int i = ty + r * 8;
    tile[i][tx] = hkw[(size_t)ch * 65536 + (size_t)(i0 + i) * 256 + e0 + tx];
  }
  __syncthreads();
#pragma unroll
  for (int r = 0; r < 4; ++r) {
    int e = ty + r * 8;
    Wt[((size_t)n * 256 + e0 + e) * 256 + i0 + tx] = f2bf(tile[tx][e]);
  }
}

// flag[l] = any(grn_g != 0); cvec[l][e] = sum_d fc2_w[l][e][d]*grn_b[l][d]
__global__ void k_prep_misc(const float* __restrict__ grng, const float* __restrict__ grnb,
                            const float* __restrict__ fc2w, int* __restrict__ flag,
                            float* __restrict__ cvec) {
  __shared__ float red[8];
  int l = blockIdx.y;
  if (blockIdx.x == 0) {
    float any = 0.f;
    for (int d = threadIdx.x; d < 1024; d += 256)
      any += (grng[l * 1024 + d] != 0.f) ? 1.f : 0.f;
    float tot = block_sum(any, red);
    if (threadIdx.x == 0) flag[l] = (tot > 0.f) ? 1 : 0;
  } else {
    int e = blockIdx.x - 1;
    float s = 0.f;
    for (int d = threadIdx.x; d < 1024; d += 256)
      s += fc2w[((size_t)(l * 256 + e) << 10) + d] * grnb[l * 1024 + d];
    float tot = block_sum(s, red);
    if (threadIdx.x == 0) cvec[l * 256 + e] = tot;
  }
}

// ======================= hyper GEMM: hb[n][e][p] = Wt[n]@xTb[b] + hkb (bf16 out) =========
__global__ void __launch_bounds__(256) k_hypm(const short* __restrict__ Wt, const short* __restrict__ xTb,
                                              const int* __restrict__ idx, const float* __restrict__ hkb,
                                              short* __restrict__ hb) {
  __shared__ short As[4096], Bs[4096];
  f32x4 acc[4][4];
  int n = blockIdx.z;
  int m0 = blockIdx.y * 128, n0 = blockIdx.x * 128;
  gemm_core<256>(Wt + (size_t)n * 65536, xTb + (size_t)(n >> 4) * 262144, m0, n0, As, Bs, acc);
  int ch = idx[n];
  const int lane = threadIdx.x & 63, wave = threadIdx.x >> 6;
  const int wr = wave >> 1, wc = wave & 1, lr = lane & 15, kg = lane >> 4;
#pragma unroll
  for (int mi = 0; mi < 4; ++mi) {
    int ebase = m0 + wr * 64 + mi * 16 + kg * 4;
#pragma unroll
    for (int ni = 0; ni < 4; ++ni) {
      int p = n0 + wc * 64 + ni * 16 + lr;
      f32x4 v = acc[mi][ni];
#pragma unroll
      for (int r = 0; r < 4; ++r)
        hb[((size_t)(n * 256 + ebase + r) << 10) + p] = f2bf(v[r] + hkb[ch * 256 + ebase + r]);
    }
  }
}

// ======================= depthwise 7x7 conv: 128 thr, 8y/thread, scalar b32 taps =========
// Proven [38][40] layout, halo-3; lanes l and l+32 differ by 8 rows = 320 floats == bank+0
// -> exactly 2 lanes/bank (free, m136). 98 reads / 8 px vs 70 / 4 px before.
__global__ void __launch_bounds__(128) k_conv(const short* __restrict__ hb, const float* __restrict__ dww,
                                              const float* __restrict__ dwb, short* __restrict__ tc, int l) {
  __shared__ float sm[38][40];
  int e = blockIdx.x, n = blockIdx.y;
  const short* plane = hb + (((size_t)(n * 256 + e)) << 10);
  const float* wv = dww + ((size_t)(l * 256 + e)) * 49;
  float w[49];
#pragma unroll
  for (int i = 0; i < 49; ++i) w[i] = wv[i];  // uniform address -> scalar loads
  int tid = threadIdx.x;
  {
    float* smf = &sm[0][0];
    for (int i = tid; i < 380; i += 128) {
      float4 z = make_float4(0.f, 0.f, 0.f, 0.f);
      *(float4*)&smf[i * 4] = z;
    }
  }
  __syncthreads();
  {
    const int* plane32 = (const int*)plane;
    for (int i = tid; i < 512; i += 128) {
      int v = plane32[i];
      int p = i * 2;
      int iy = p >> 5, ix = p & 31;
      sm[iy + 3][ix + 3] = bf2f((short)(v & 0xffff));
      sm[iy + 3][ix + 4] = bf2f((short)(v >> 16));
    }
  }
  __syncthreads();
  int x = tid & 31, y0 = (tid >> 5) * 8;
  float bias = dwb[l * 256 + e];
  float acc[8];
#pragma unroll
  for (int j = 0; j < 8; ++j) acc[j] = bias;
#pragma unroll
  for (int r = 0; r < 14; ++r) {
#pragma unroll
    for (int c = 0; c < 7; ++c) {
      float v = sm[y0 + r][x + c];
#pragma unroll
      for (int j = 0; j < 8; ++j) {
        if (j >= r - 6 && j <= r)  // compile-time predicate after unroll
          acc[j] = __builtin_fmaf(v, w[(r - j) * 7 + c], acc[j]);
      }
    }
  }
  short* outp = tc + (((size_t)(n * 256 + e)) << 10) + y0 * 32 + x;
#pragma unroll
  for (int j = 0; j < 8; ++j) outp[j * 32] = f2bf(acc[j]);
}

// ======================= LayerNorm + NCHW->NHWC transpose (tc -> tb, SWIZZLED store) =====
// tc reads vectorized: int4 = 8 shorts along p (G13).
__global__ void __launch_bounds__(256) k_ln(const short* __restrict__ tc, const float* __restrict__ lng,
                                            const float* __restrict__ lnb, short* __restrict__ tb,
                                            float* __restrict__ gx, const int* __restrict__ flag, int l) {
  __shared__ float smT[32][261];
  __shared__ float muS[32], rsS[32];
  int n = blockIdx.y, p0 = blockIdx.x * 32;
  int tid = threadIdx.x;
  if (blockIdx.x == 0 && flag[l] != 0) {
#pragma unroll
    for (int r = 0; r < 4; ++r) gx[n * 1024 + r * 256 + tid] = 0.f;
  }
  const short* base = tc + ((size_t)n << 18) + p0;
#pragma unroll
  for (int it = 0; it < 4; ++it) {
    int i = it * 256 + tid;          // 0..1023
    int e = i >> 2, pq = (i & 3) * 8;
    int4 v = *(const int4*)&base[(e << 10) + pq];
    short s[8];
    *(int4*)s = v;
#pragma unroll
    for (int j = 0; j < 8; ++j) smT[pq + j][e] = bf2f(s[j]);
  }
  __syncthreads();
  {
    int j = tid & 7, p = tid >> 3;
    float s = 0.f, q = 0.f;
#pragma unroll
    for (int i = 0; i < 32; ++i) {
      float v = smT[p][j + i * 8];
      s += v; q += v * v;
    }
    s += __shfl_xor(s, 1); q += __shfl_xor(q, 1);
    s += __shfl_xor(s, 2); q += __shfl_xor(q, 2);
    s += __shfl_xor(s, 4); q += __shfl_xor(q, 4);
    if (j == 0) {
      float mu = s * (1.f / 256.f);
      float var = q * (1.f / 256.f) - mu * mu;
      muS[p] = mu;
      rsS[p] = rsqrtf(fmaxf(var, 0.f) + 1e-5f);
    }
  }
  __syncthreads();
  for (int i = tid; i < 8192; i += 256) {
    int p = i >> 8, e = i & 255;
    int px = n * 1024 + p0 + p;
    float v = (smT[p][e] - muS[p]) * rsS[p] * lng[l * 256 + e] + lnb[l * 256 + e];
    int es = (e & 0xC0) | ((((e >> 3) & 7) ^ (px & 7)) << 3) | (e & 7);
    tb[((size_t)px) * 256 + es] = f2bf(v);
  }
}

// ======================= GRN general path (flag-gated; no-op for this data) ==============
__global__ void __launch_bounds__(256) k_gx1(const short* __restrict__ w1b, const short* __restrict__ tb,
                                             const float* __restrict__ fc1b, float* __restrict__ gx,
                                             const int* __restrict__ flag, int l) {
  if (flag[l] == 0) return;
  __shared__ short As[8192], Bs[8192];
  f32x4 acc[4][4];
  int m0 = blockIdx.y * 128, n0 = blockIdx.x * 128;
  gemm_core_k64<256>(w1b + (size_t)l * 262144, tb, m0, n0, As, Bs, acc);
  const int lane = threadIdx.x & 63, wave = threadIdx.x >> 6;
  const int wr = wave >> 1, kg = lane >> 4;
  int n = (n0 >> 10);
#pragma unroll
  for (int mi = 0; mi < 4; ++mi) {
    int dbase = m0 + wr * 64 + mi * 16 + kg * 4;
#pragma unroll
    for (int ni = 0; ni < 4; ++ni) {
      f32x4 v = acc[mi][ni];
#pragma unroll
      for (int r = 0; r < 4; ++r) {
        float g = gelu(v[r] + fc1b[l * 1024 + dbase + r]);
        atomicAdd(&gx[n * 1024 + dbase + r], g * g);
      }
    }
  }
}

__global__ void k_nx(const float* __restrict__ gx, float* __restrict__ nx,
                     const int* __restrict__ flag, int l) {
  int n = blockIdx.x, tid = threadIdx.x;
  if (flag[l] == 0) {
    for (int d = tid; d < 1024; d += 256) nx[n * 1024 + d] = 0.f;
    return;
  }
  __shared__ float red[8];
  __shared__ float sv[1024];
  float s = 0.f;
  for (int d = tid; d < 1024; d += 256) {
    float v = sqrtf(gx[n * 1024 + d]);
    sv[d] = v; s += v;
  }
  float tot = block_sum(s, red);
  float mean = tot * (1.f / 1024.f);
  for (int d = tid; d < 1024; d += 256) nx[n * 1024 + d] = sv[d] / (mean + 1e-6f);
}

// ======================= fc1 (BK=64 swizzled core): u = gelu(tb@W1^T+b1)*(1+g*nx) ========
// 1D grid 2048 = 8 XCD x 32 n-tiles x 8 m-tiles
__global__ void __launch_bounds__(256) k_fc1(const short* __restrict__ w1b, const short* __restrict__ tb,
                                             const float* __restrict__ fc1b, const float* __restrict__ grng,
                                             const float* __restrict__ nx, short* __restrict__ u,
                                             int l, int cbase) {
  __shared__ short As[8192], Bs[8192];
  f32x4 acc[4][4];
  int bid = blockIdx.x;
  int xcd = bid & 7, loc = bid >> 3;
  int nt = (xcd << 5) + (loc >> 3);   // 0..255
  int mt = loc & 7;                   // 0..7
  int m0 = mt * 128, n0 = nt * 128;
  gemm_core_k64<256>(w1b + (size_t)l * 262144, tb + (size_t)cbase * 256, m0, n0, As, Bs, acc);
  const int lane = threadIdx.x & 63, wave = threadIdx.x >> 6;
  const int wr = wave >> 1, wc = wave & 1, lr = lane & 15, kg = lane >> 4;
  int nimg = (cbase + n0) >> 10;
#pragma unroll
  for (int mi = 0; mi < 4; ++mi) {
    int dbase = m0 + wr * 64 + mi * 16 + kg * 4;
    float b0 = fc1b[l * 1024 + dbase + 0], b1 = fc1b[l * 1024 + dbase + 1];
    float b2 = fc1b[l * 1024 + dbase + 2], b3 = fc1b[l * 1024 + dbase + 3];
    float a0 = 1.f + grng[l * 1024 + dbase + 0] * nx[nimg * 1024 + dbase + 0];
    float a1 = 1.f + grng[l * 1024 + dbase + 1] * nx[nimg * 1024 + dbase + 1];
    float a2 = 1.f + grng[l * 1024 + dbase + 2] * nx[nimg * 1024 + dbase + 2];
    float a3 = 1.f + grng[l * 1024 + dbase + 3] * nx[nimg * 1024 + dbase + 3];
#pragma unroll
    for (int ni = 0; ni < 4; ++ni) {
      int pl = n0 + wc * 64 + ni * 16 + lr;
      f32x4 v = acc[mi][ni];
      short4 sv;
      sv.x = f2bf(gelu(v[0] + b0) * a0);
      sv.y = f2bf(gelu(v[1] + b1) * a1);
      sv.z = f2bf(gelu(v[2] + b2) * a2);
      sv.w = f2bf(gelu(v[3] + b3) * a3);
      *(short4*)&u[(size_t)pl * 1024 + dbase] = sv;
    }
  }
}

// ======================= fc2 (128x64 tile, XCD-chunked): hb += u@W2^T + b2 + cvec ========
// 1D grid 1024 = 8 XCD x 64 n-tiles x 2 m-tiles
template <int LAST>
__global__ void __launch_bounds__(256) k_fc2(const short* __restrict__ w2b, const short* __restrict__ u,
                                             const float* __restrict__ fc2b, const float* __restrict__ cvec,
                                             short* __restrict__ hb, short* __restrict__ ht,
                                             int l, int cbase) {
  __shared__ short As[4096], Bs[2048];
  f32x4 acc[4][2];
  int bid = blockIdx.x;
  int xcd = bid & 7, loc = bid >> 3;
  int nt = (xcd << 6) + (loc >> 1);   // 0..511
  int mt = loc & 1;                   // 0..1
  int m0 = mt * 128, n0 = nt * 64;
  gemm_core_n64<1024>(w2b + (size_t)l * 262144, u, m0, n0, As, Bs, acc);
  const int lane = threadIdx.x & 63, wave = threadIdx.x >> 6;
  const int wr = wave >> 1, wc = wave & 1, lr = lane & 15, kg = lane >> 4;
#pragma unroll
  for (int mi = 0; mi < 4; ++mi) {
    int ebase = m0 + wr * 64 + mi * 16 + kg * 4;
    float add0 = fc2b[l * 256 + ebase + 0] + cvec[l * 256 + ebase + 0];
    float add1 = fc2b[l * 256 + ebase + 1] + cvec[l * 256 + ebase + 1];
    float add2 = fc2b[l * 256 + ebase + 2] + cvec[l * 256 + ebase + 2];
    float add3 = fc2b[l * 256 + ebase + 3] + cvec[l * 256 + ebase + 3];
#pragma unroll
    for (int ni = 0; ni < 2; ++ni) {
      int P = cbase + n0 + wc * 32 + ni * 16 + lr;
      int n = P >> 10, p = P & 1023;
      f32x4 v = acc[mi][ni];
      short* hp0 = &hb[((size_t)(n * 256 + ebase) << 10) + p];
      float r0 = v[0] + add0 + bf2f(hp0[0]);
      float r1 = v[1] + add1 + bf2f(hp0[1 << 10]);
      float r2 = v[2] + add2 + bf2f(hp0[2 << 10]);
      float r3 = v[3] + add3 + bf2f(hp0[3 << 10]);
      if (LAST) {
        short* hr = &ht[(size_t)P * 256 + ebase];
        hr[0] = f2bf(r0); hr[1] = f2bf(r1); hr[2] = f2bf(r2); hr[3] = f2bf(r3);
      } else {
        hp0[0] = f2bf(r0); hp0[1 << 10] = f2bf(r1); hp0[2 << 10] = f2bf(r2); hp0[3 << 10] = f2bf(r3);
      }
    }
  }
}

// ======================= pred: MFMA GEMM (32 x 65536 x 256) + fused pixel shuffle ========
__global__ void __launch_bounds__(128) k_pred2(const short* __restrict__ ht, const float* __restrict__ pw,
                                               const float* __restrict__ pb, float* __restrict__ out) {
  __shared__ short Aw[32 * 264];
  __shared__ short Bl[256 * 32];
  int tid = threadIdx.x;
  int n0 = blockIdx.x * 256;
  for (int i = tid; i < 8192; i += 128) {
    int o = i >> 8, e = i & 255;
    Aw[o * 264 + e] = f2bf(pw[i]);
  }
  const int lane = tid & 63, wave = tid >> 6;
  const int lr = lane & 15, kg = lane >> 4;
  const int sr = lane >> 2, sc = (lane & 3) * 8;
  f32x4 acc[2][8];
#pragma unroll
  for (int mi = 0; mi < 2; ++mi)
#pragma unroll
    for (int ni = 0; ni < 8; ++ni) acc[mi][ni] = f32x4{0.f, 0.f, 0.f, 0.f};
  __syncthreads();
  for (int k0 = 0; k0 < 256; k0 += 32) {
#pragma unroll
    for (int j = 0; j < 8; ++j) {
      int rb = wave * 128 + j * 16;
      gload16(ht + (size_t)(n0 + rb + sr) * 256 + k0 + sc, Bl + rb * 32);
    }
    __syncthreads();
    bf16x8 af[2], bfr[8];
#pragma unroll
    for (int mi = 0; mi < 2; ++mi) af[mi] = *(const bf16x8*)&Aw[(mi * 16 + lr) * 264 + k0 + kg * 8];
#pragma unroll
    for (int ni = 0; ni < 8; ++ni) bfr[ni] = *(const bf16x8*)&Bl[(wave * 128 + ni * 16 + lr) * 32 + kg * 8];
#pragma unroll
    for (int mi = 0; mi < 2; ++mi)
#pragma unroll
      for (int ni = 0; ni < 8; ++ni)
        acc[mi][ni] = __builtin_amdgcn_mfma_f32_16x16x32_bf16(af[mi], bfr[ni], acc[mi][ni], 0, 0, 0);
    __syncthreads();
  }
#pragma unroll
  for (int mi = 0; mi < 2; ++mi) {
#pragma unroll
    for (int ni = 0; ni < 8; ++ni) {
      int P = n0 + wave * 128 + ni * 16 + lr;
      int n = P >> 10, p = P & 1023;
      int y = p >> 5, xx = p & 31;
      f32x4 v = acc[mi][ni];
#pragma unroll
      for (int r = 0; r < 4; ++r) {
        int o = mi * 16 + kg * 4 + r;
        int s1 = o >> 3, s2 = (o >> 1) & 3, tt = o & 1;
        size_t oi = (((size_t)n * 128 + y * 4 + s1) * 128 + xx * 4 + s2) * 2 + tt;
        out[oi] = v[r] + pb[o];
      }
    }
  }
}

extern "C" void kernel_launch(void* const* d_in, const int* in_sizes, int n_in,
                              void* d_out, int out_size, void* d_ws, size_t ws_size,
                              hipStream_t stream) {
  const float* x    = (const float*)d_in[0];
  const int*   idx  = (const int*)d_in[1];
  const float* hkw  = (const float*)d_in[2];
  const float* hkb  = (const float*)d_in[3];
  const float* dww  = (const float*)d_in[4];
  const float* dwb  = (const float*)d_in[5];
  const float* lng  = (const float*)d_in[6];
  const float* lnb  = (const float*)d_in[7];
  const float* fc1w = (const float*)d_in[8];
  const float* fc1b = (const float*)d_in[9];
  const float* grng = (const float*)d_in[10];
  const float* grnb = (const float*)d_in[11];
  const float* fc2w = (const float*)d_in[12];
  const float* fc2b = (const float*)d_in[13];
  const float* pw   = (const float*)d_in[14];
  const float* pb   = (const float*)d_in[15];
  float* out = (float*)d_out;

  char* ws = (char*)d_ws;
  short* hb   = (short*)(ws);                            // bf16 residual NCHW
  short* tb   = (short*)(ws + (32ull << 20));            // LN'd NHWC (swizzled); ht last layer
  short* u    = (short*)(ws + (64ull << 20));            // 64MB: 32-image hidden chunk
  short* tc   = (short*)(ws + (64ull << 20));            // overlay (conv->ln only)
  short* Wt   = (short*)(ws + (64ull << 20));            // overlay (prologue only)
  short* xTb  = (short*)(ws + (72ull << 20));            // overlay (prologue only)
  short* w1b  = (short*)(ws + (128ull << 20));
  short* w2b  = (short*)(ws + (130ull << 20));
  float* gx   = (float*)(ws + (132ull << 20));
  float* nx   = (float*)(ws + (132ull << 20) + (1 << 18));
  float* cvec = (float*)(ws + (132ull << 20) + (2 << 18));
  int*   flag = (int*)  (ws + (132ull << 20) + (2 << 18) + 4096);

  k_cvt_w<<<4096, 256, 0, stream>>>(fc1w, fc2w, w1b, w2b);
  k_prep_misc<<<dim3(257, 4), 256, 0, stream>>>(grng, grnb, fc2w, flag, cvec);
  k_prep_xt<<<dim3(32, 8, 4), 256, 0, stream>>>(x, xTb);
  k_prep_wt<<<dim3(8, 8, 64), 256, 0, stream>>>(hkw, idx, Wt);
  k_hypm<<<dim3(8, 2, 64), 256, 0, stream>>>(Wt, xTb, idx, hkb, hb);
  for (int l = 0; l < 4; ++l) {
    k_conv<<<dim3(256, 64), 128, 0, stream>>>(hb, dww, dwb, tc, l);
    k_ln<<<dim3(32, 64), 256, 0, stream>>>(tc, lng, lnb, tb, gx, flag, l);
    k_gx1<<<dim3(512, 8), 256, 0, stream>>>(w1b, tb, fc1b, gx, flag, l);
    k_nx<<<64, 256, 0, stream>>>(gx, nx, flag, l);
    for (int c = 0; c < 2; ++c) {
      int cbase = c * 32768;
      k_fc1<<<2048, 256, 0, stream>>>(w1b, tb, fc1b, grng, nx, u, l, cbase);
      if (l < 3)
        k_fc2<0><<<1024, 256, 0, stream>>>(w2b, u, fc2b, cvec, hb, tb, l, cbase);
      else
        k_fc2<1><<<1024, 256, 0, stream>>>(w2b, u, fc2b, cvec, hb, tb, l, cbase);
    }
  }
  k_pred2<<<256, 128, 0, stream>>>(tb, pw, pb, out);
}

// Round 17
// 774.173 us; speedup vs baseline: 1.3885x; 1.0478x over previous
//
#include <hip/hip_runtime.h>
#include <hip/hip_bf16.h>
#include <math.h>

// B=4, C=16 -> N=64 images; E=256; H=W=32 -> P=1024/img, 65536 total; I=256; HID=1024; L=4
// ws layout (~132.6MB):
//   hb   bf16[64][256][1024]  @0      32MB   residual stream (NCHW, bf16)
//   tb   bf16[65536][256]     @32MB   32MB   LN'd NHWC, SLOT-SWIZZLED (s^=(px&7) per 128B blk);
//                                            final-layer ht (unswizzled) overwrites consumed rows
//   u    bf16[32768][1024]    @64MB   64MB   hidden chunk (32 images, 2 chunks/layer)
//     overlays in u region: tc bf16[64][256][1024]; Wt @64MB; xTb @72MB (prologue)
//   w1b  @128MB 2MB (SLOT-SWIZZLED by d&7); w2b @130MB 2MB (plain); gx @132MB; nx; cvec; flag

typedef __attribute__((ext_vector_type(8))) __bf16 bf16x8;
typedef __attribute__((ext_vector_type(4))) float f32x4;

__device__ __forceinline__ short f2bf(float f) {
  unsigned u = __float_as_uint(f);
  unsigned r = (u + 0x7FFFu + ((u >> 16) & 1u)) >> 16;
  return (short)r;
}
__device__ __forceinline__ float bf2f(short s) {
  return __uint_as_float(((unsigned)(unsigned short)s) << 16);
}
__device__ __forceinline__ int pack2(short a, short b) {
  return (int)(unsigned short)a | ((int)(unsigned short)b << 16);
}
// tanh-approx GELU, sigmoid form, hardware rcp (v_rcp_f32; ~1e-7 rel err)
__device__ __forceinline__ float gelu(float x) {
  float t = __builtin_fmaf(0.0713548162f * x * x, x, 1.59576912f * x);
  return x * __builtin_amdgcn_rcpf(1.f + __expf(-t));
}

__device__ __forceinline__ void gload16(const short* g, short* l) {
  __builtin_amdgcn_global_load_lds(
      (const __attribute__((address_space(1))) void*)(g),
      (__attribute__((address_space(3))) void*)(l), 16, 0, 0);
}

__device__ __forceinline__ float block_sum(float v, float* red) {
#pragma unroll
  for (int o = 32; o > 0; o >>= 1) v += __shfl_down(v, o);
  int lane = threadIdx.x & 63, w = threadIdx.x >> 6;
  int nw = blockDim.x >> 6;
  if (lane == 0) red[w] = v;
  __syncthreads();
  if (threadIdx.x == 0) {
    float s = 0.f;
    for (int i = 0; i < nw; ++i) s += red[i];
    red[0] = s;
  }
  __syncthreads();
  float s = red[0];
  __syncthreads();
  return s;
}

// ======================= MFMA GEMM core (BK=32, linear LDS; m97 structure) ==============
template <int K>
__device__ __forceinline__ void gemm_core(const short* __restrict__ A, const short* __restrict__ Bt,
                                          int m0, int n0, short* As, short* Bs, f32x4 acc[4][4]) {
  const int tid = threadIdx.x;
  const int lane = tid & 63, wave = tid >> 6;
  const int wr = wave >> 1, wc = wave & 1;
  const int lr = lane & 15, kg = lane >> 4;
#pragma unroll
  for (int mi = 0; mi < 4; ++mi)
#pragma unroll
    for (int ni = 0; ni < 4; ++ni) acc[mi][ni] = f32x4{0.f, 0.f, 0.f, 0.f};
  const int sr = lane >> 2, sc = (lane & 3) * 8;
  const int ra0 = wave * 16, ra1 = wave * 16 + 64;
  const short* Ab = A + (size_t)m0 * K;
  const short* Bb = Bt + (size_t)n0 * K;
  for (int k0 = 0; k0 < K; k0 += 32) {
    gload16(Ab + (size_t)(ra0 + sr) * K + k0 + sc, As + ra0 * 32);
    gload16(Ab + (size_t)(ra1 + sr) * K + k0 + sc, As + ra1 * 32);
    gload16(Bb + (size_t)(ra0 + sr) * K + k0 + sc, Bs + ra0 * 32);
    gload16(Bb + (size_t)(ra1 + sr) * K + k0 + sc, Bs + ra1 * 32);
    __syncthreads();
    bf16x8 af[4], bfr[4];
#pragma unroll
    for (int mi = 0; mi < 4; ++mi) af[mi] = *(const bf16x8*)&As[(wr * 64 + mi * 16 + lr) * 32 + kg * 8];
#pragma unroll
    for (int ni = 0; ni < 4; ++ni) bfr[ni] = *(const bf16x8*)&Bs[(wc * 64 + ni * 16 + lr) * 32 + kg * 8];
#pragma unroll
    for (int mi = 0; mi < 4; ++mi)
#pragma unroll
      for (int ni = 0; ni < 4; ++ni)
        acc[mi][ni] = __builtin_amdgcn_mfma_f32_16x16x32_bf16(af[mi], bfr[ni], acc[mi][ni], 0, 0, 0);
    __syncthreads();
  }
}

// ======================= MFMA GEMM core (BK=64, swizzled operands) ======================
// A,Bt pre-swizzled in GLOBAL memory: 16B slot j of each 128B block of row r holds slot j^(r&7).
template <int K>
__device__ __forceinline__ void gemm_core_k64(const short* __restrict__ A, const short* __restrict__ Bt,
                                              int m0, int n0, short* As, short* Bs, f32x4 acc[4][4]) {
  const int tid = threadIdx.x;
  const int lane = tid & 63, wave = tid >> 6;
  const int wr = wave >> 1, wc = wave & 1;
  const int lr = lane & 15, kg = lane >> 4;
#pragma unroll
  for (int mi = 0; mi < 4; ++mi)
#pragma unroll
    for (int ni = 0; ni < 4; ++ni) acc[mi][ni] = f32x4{0.f, 0.f, 0.f, 0.f};
  const int sr = lane >> 3;          // 0..7
  const int sc = (lane & 7) * 8;     // 0..56
  const short* Ab = A + (size_t)m0 * K;
  const short* Bb = Bt + (size_t)n0 * K;
  for (int k0 = 0; k0 < K; k0 += 64) {
#pragma unroll
    for (int j = 0; j < 4; ++j) {
      int r = wave * 8 + j * 32;
      gload16(Ab + (size_t)(r + sr) * K + k0 + sc, As + r * 64);
      gload16(Bb + (size_t)(r + sr) * K + k0 + sc, Bs + r * 64);
    }
    __syncthreads();
#pragma unroll
    for (int ks = 0; ks < 2; ++ks) {
      bf16x8 af[4], bfr[4];
#pragma unroll
      for (int mi = 0; mi < 4; ++mi) {
        int R = wr * 64 + mi * 16 + lr;
        int s = ks * 4 + kg;
        af[mi] = *(const bf16x8*)&As[R * 64 + ((s ^ (R & 7)) << 3)];
      }
#pragma unroll
      for (int ni = 0; ni < 4; ++ni) {
        int R = wc * 64 + ni * 16 + lr;
        int s = ks * 4 + kg;
        bfr[ni] = *(const bf16x8*)&Bs[R * 64 + ((s ^ (R & 7)) << 3)];
      }
#pragma unroll
      for (int mi = 0; mi < 4; ++mi)
#pragma unroll
        for (int ni = 0; ni < 4; ++ni)
          acc[mi][ni] = __builtin_amdgcn_mfma_f32_16x16x32_bf16(af[mi], bfr[ni], acc[mi][ni], 0, 0, 0);
    }
    __syncthreads();
  }
}

// ======================= MFMA GEMM core, 128(m) x 64(n) tile (BK=32, linear) ============
template <int K>
__device__ __forceinline__ void gemm_core_n64(const short* __restrict__ A, const short* __restrict__ Bt,
                                              int m0, int n0, short* As, short* Bs, f32x4 acc[4][2]) {
  const int tid = threadIdx.x;
  const int lane = tid & 63, wave = tid >> 6;
  const int wr = wave >> 1, wc = wave & 1;
  const int lr = lane & 15, kg = lane >> 4;
#pragma unroll
  for (int mi = 0; mi < 4; ++mi)
#pragma unroll
    for (int ni = 0; ni < 2; ++ni) acc[mi][ni] = f32x4{0.f, 0.f, 0.f, 0.f};
  const int sr = lane >> 2, sc = (lane & 3) * 8;
  const int ra0 = wave * 16, ra1 = wave * 16 + 64;
  const short* Ab = A + (size_t)m0 * K;
  const short* Bb = Bt + (size_t)n0 * K;
  for (int k0 = 0; k0 < K; k0 += 32) {
    gload16(Ab + (size_t)(ra0 + sr) * K + k0 + sc, As + ra0 * 32);
    gload16(Ab + (size_t)(ra1 + sr) * K + k0 + sc, As + ra1 * 32);
    gload16(Bb + (size_t)(ra0 + sr) * K + k0 + sc, Bs + ra0 * 32);
    __syncthreads();
    bf16x8 af[4], bfr[2];
#pragma unroll
    for (int mi = 0; mi < 4; ++mi) af[mi] = *(const bf16x8*)&As[(wr * 64 + mi * 16 + lr) * 32 + kg * 8];
#pragma unroll
    for (int ni = 0; ni < 2; ++ni) bfr[ni] = *(const bf16x8*)&Bs[(wc * 32 + ni * 16 + lr) * 32 + kg * 8];
#pragma unroll
    for (int mi = 0; mi < 4; ++mi)
#pragma unroll
      for (int ni = 0; ni < 2; ++ni)
        acc[mi][ni] = __builtin_amdgcn_mfma_f32_16x16x32_bf16(af[mi], bfr[ni], acc[mi][ni], 0, 0, 0);
    __syncthreads();
  }
}

// ======================= prep kernels =======================
// w1b stored SLOT-SWIZZLED: 16B slot j within each 64-short block moves to j ^ (d&7).
__global__ void k_cvt_w(const float* __restrict__ fc1w, const float* __restrict__ fc2w,
                        short* __restrict__ w1b, short* __restrict__ w2b) {
  int i = blockIdx.x * 256 + threadIdx.x;  // 4*262144
  int d7 = (i >> 8) & 7;
  int e = i & 255;
  int es = (e & 0xC0) | (((((e >> 3) & 7) ^ d7)) << 3) | (e & 7);
  w1b[(i & ~255) | es] = f2bf(fc1w[i]);
  w2b[i] = f2bf(fc2w[i]);
}

// x [4][256 i][1024 p] f32 -> xTb [4][1024 p][256 i] bf16
__global__ void k_prep_xt(const float* __restrict__ x, short* __restrict__ xTb) {
  __shared__ float tile[32][33];
  int tx = threadIdx.x & 31, ty = threadIdx.x >> 5;
  int p0 = blockIdx.x * 32, i0 = blockIdx.y * 32, b = blockIdx.z;
#pragma unroll
  for (int r = 0; r < 4; ++r) {
    int i = ty + r * 8;
    tile[i][tx] = x[((size_t)b * 256 + i0 + i) * 1024 + p0 + tx];
  }
  __syncthreads();
#pragma unroll
  for (int r = 0; r < 4; ++r) {
    int p = ty + r * 8;
    xTb[((size_t)b * 1024 + p0 + p) * 256 + i0 + tx] = f2bf(tile[tx][p]);
  }
}

// hk_w gather+transpose: Wt[n][e][i] bf16 = hkw[idx[n]][i][e]
__global__ void k_prep_wt(const float* __restrict__ hkw, const int* __restrict__ idx,
                          short* __restrict__ Wt) {
  __shared__ float tile[32][33];
  int tx = threadIdx.x & 31, ty = threadIdx.x >> 5;
  int e0 = blockIdx.x * 32, i0 = blockIdx.y * 32, n = blockIdx.z;
  int ch = idx[n];
#pragma unroll
  for (int r = 0; r < 4; ++r) {
    int i = ty + r * 8;
    tile[i][tx] = hkw[(size_t)ch * 65536 + (size_t)(i0 + i) * 256 + e0 + tx];
  }
  __syncthreads();
#pragma unroll
  for (int r = 0; r < 4; ++r) {
    int e = ty + r * 8;
    Wt[((size_t)n * 256 + e0 + e) * 256 + i0 + tx] = f2bf(tile[tx][e]);
  }
}

// flag[l] = any(grn_g != 0); cvec[l][e] = sum_d fc2_w[l][e][d]*grn_b[l][d]
__global__ void k_prep_misc(const float* __restrict__ grng, const float* __restrict__ grnb,
                            const float* __restrict__ fc2w, int* __restrict__ flag,
                            float* __restrict__ cvec) {
  __shared__ float red[8];
  int l = blockIdx.y;
  if (blockIdx.x == 0) {
    float any = 0.f;
    for (int d = threadIdx.x; d < 1024; d += 256)
      any += (grng[l * 1024 + d] != 0.f) ? 1.f : 0.f;
    float tot = block_sum(any, red);
    if (threadIdx.x == 0) flag[l] = (tot > 0.f) ? 1 : 0;
  } else {
    int e = blockIdx.x - 1;
    float s = 0.f;
    for (int d = threadIdx.x; d < 1024; d += 256)
      s += fc2w[((size_t)(l * 256 + e) << 10) + d] * grnb[l * 1024 + d];
    float tot = block_sum(s, red);
    if (threadIdx.x == 0) cvec[l * 256 + e] = tot;
  }
}

// ======================= hyper GEMM: hb[n][e][p] = Wt[n]@xTb[b] + hkb (bf16 out) =========
__global__ void __launch_bounds__(256) k_hypm(const short* __restrict__ Wt, const short* __restrict__ xTb,
                                              const int* __restrict__ idx, const float* __restrict__ hkb,
                                              short* __restrict__ hb) {
  __shared__ short As[4096], Bs[4096];
  f32x4 acc[4][4];
  int n = blockIdx.z;
  int m0 = blockIdx.y * 128, n0 = blockIdx.x * 128;
  gemm_core<256>(Wt + (size_t)n * 65536, xTb + (size_t)(n >> 4) * 262144, m0, n0, As, Bs, acc);
  int ch = idx[n];
  const int lane = threadIdx.x & 63, wave = threadIdx.x >> 6;
  const int wr = wave >> 1, wc = wave & 1, lr = lane & 15, kg = lane >> 4;
#pragma unroll
  for (int mi = 0; mi < 4; ++mi) {
    int ebase = m0 + wr * 64 + mi * 16 + kg * 4;
#pragma unroll
    for (int ni = 0; ni < 4; ++ni) {
      int p = n0 + wc * 64 + ni * 16 + lr;
      f32x4 v = acc[mi][ni];
#pragma unroll
      for (int r = 0; r < 4; ++r)
        hb[((size_t)(n * 256 + ebase + r) << 10) + p] = f2bf(v[r] + hkb[ch * 256 + ebase + r]);
    }
  }
}

// ======================= depthwise 7x7 conv: 128 thr, 8y/thread, scalar b32 taps =========
__global__ void __launch_bounds__(128) k_conv(const short* __restrict__ hb, const float* __restrict__ dww,
                                              const float* __restrict__ dwb, short* __restrict__ tc, int l) {
  __shared__ float sm[38][40];
  int e = blockIdx.x, n = blockIdx.y;
  const short* plane = hb + (((size_t)(n * 256 + e)) << 10);
  const float* wv = dww + ((size_t)(l * 256 + e)) * 49;
  float w[49];
#pragma unroll
  for (int i = 0; i < 49; ++i) w[i] = wv[i];  // uniform address -> scalar loads
  int tid = threadIdx.x;
  {
    float* smf = &sm[0][0];
    for (int i = tid; i < 380; i += 128) {
      float4 z = make_float4(0.f, 0.f, 0.f, 0.f);
      *(float4*)&smf[i * 4] = z;
    }
  }
  __syncthreads();
  {
    const int* plane32 = (const int*)plane;
    for (int i = tid; i < 512; i += 128) {
      int v = plane32[i];
      int p = i * 2;
      int iy = p >> 5, ix = p & 31;
      sm[iy + 3][ix + 3] = bf2f((short)(v & 0xffff));
      sm[iy + 3][ix + 4] = bf2f((short)(v >> 16));
    }
  }
  __syncthreads();
  int x = tid & 31, y0 = (tid >> 5) * 8;
  float bias = dwb[l * 256 + e];
  float acc[8];
#pragma unroll
  for (int j = 0; j < 8; ++j) acc[j] = bias;
#pragma unroll
  for (int r = 0; r < 14; ++r) {
#pragma unroll
    for (int c = 0; c < 7; ++c) {
      float v = sm[y0 + r][x + c];
#pragma unroll
      for (int j = 0; j < 8; ++j) {
        if (j >= r - 6 && j <= r)  // compile-time predicate after unroll
          acc[j] = __builtin_fmaf(v, w[(r - j) * 7 + c], acc[j]);
      }
    }
  }
  short* outp = tc + (((size_t)(n * 256 + e)) << 10) + y0 * 32 + x;
#pragma unroll
  for (int j = 0; j < 8; ++j) outp[j * 32] = f2bf(acc[j]);
}

// ======================= LayerNorm + NCHW->NHWC transpose (tc -> tb, SWIZZLED store) =====
__global__ void __launch_bounds__(256) k_ln(const short* __restrict__ tc, const float* __restrict__ lng,
                                            const float* __restrict__ lnb, short* __restrict__ tb,
                                            float* __restrict__ gx, const int* __restrict__ flag, int l) {
  __shared__ float smT[32][261];
  __shared__ float muS[32], rsS[32];
  int n = blockIdx.y, p0 = blockIdx.x * 32;
  int tid = threadIdx.x;
  if (blockIdx.x == 0 && flag[l] != 0) {
#pragma unroll
    for (int r = 0; r < 4; ++r) gx[n * 1024 + r * 256 + tid] = 0.f;
  }
  const short* base = tc + ((size_t)n << 18) + p0;
#pragma unroll
  for (int it = 0; it < 4; ++it) {
    int i = it * 256 + tid;          // 0..1023
    int e = i >> 2, pq = (i & 3) * 8;
    int4 v = *(const int4*)&base[(e << 10) + pq];
    short s[8];
    *(int4*)s = v;
#pragma unroll
    for (int j = 0; j < 8; ++j) smT[pq + j][e] = bf2f(s[j]);
  }
  __syncthreads();
  {
    int j = tid & 7, p = tid >> 3;
    float s = 0.f, q = 0.f;
#pragma unroll
    for (int i = 0; i < 32; ++i) {
      float v = smT[p][j + i * 8];
      s += v; q += v * v;
    }
    s += __shfl_xor(s, 1); q += __shfl_xor(q, 1);
    s += __shfl_xor(s, 2); q += __shfl_xor(q, 2);
    s += __shfl_xor(s, 4); q += __shfl_xor(q, 4);
    if (j == 0) {
      float mu = s * (1.f / 256.f);
      float var = q * (1.f / 256.f) - mu * mu;
      muS[p] = mu;
      rsS[p] = rsqrtf(fmaxf(var, 0.f) + 1e-5f);
    }
  }
  __syncthreads();
  for (int i = tid; i < 8192; i += 256) {
    int p = i >> 8, e = i & 255;
    int px = n * 1024 + p0 + p;
    float v = (smT[p][e] - muS[p]) * rsS[p] * lng[l * 256 + e] + lnb[l * 256 + e];
    int es = (e & 0xC0) | ((((e >> 3) & 7) ^ (px & 7)) << 3) | (e & 7);
    tb[((size_t)px) * 256 + es] = f2bf(v);
  }
}

// ======================= GRN general path (flag-gated; no-op for this data) ==============
__global__ void __launch_bounds__(256) k_gx1(const short* __restrict__ w1b, const short* __restrict__ tb,
                                             const float* __restrict__ fc1b, float* __restrict__ gx,
                                             const int* __restrict__ flag, int l) {
  if (flag[l] == 0) return;
  __shared__ short As[8192], Bs[8192];
  f32x4 acc[4][4];
  int m0 = blockIdx.y * 128, n0 = blockIdx.x * 128;
  gemm_core_k64<256>(w1b + (size_t)l * 262144, tb, m0, n0, As, Bs, acc);
  const int lane = threadIdx.x & 63, wave = threadIdx.x >> 6;
  const int wr = wave >> 1, kg = lane >> 4;
  int n = (n0 >> 10);
#pragma unroll
  for (int mi = 0; mi < 4; ++mi) {
    int dbase = m0 + wr * 64 + mi * 16 + kg * 4;
#pragma unroll
    for (int ni = 0; ni < 4; ++ni) {
      f32x4 v = acc[mi][ni];
#pragma unroll
      for (int r = 0; r < 4; ++r) {
        float g = gelu(v[r] + fc1b[l * 1024 + dbase + r]);
        atomicAdd(&gx[n * 1024 + dbase + r], g * g);
      }
    }
  }
}

__global__ void k_nx(const float* __restrict__ gx, float* __restrict__ nx,
                     const int* __restrict__ flag, int l) {
  int n = blockIdx.x, tid = threadIdx.x;
  if (flag[l] == 0) {
    for (int d = tid; d < 1024; d += 256) nx[n * 1024 + d] = 0.f;
    return;
  }
  __shared__ float red[8];
  __shared__ float sv[1024];
  float s = 0.f;
  for (int d = tid; d < 1024; d += 256) {
    float v = sqrtf(gx[n * 1024 + d]);
    sv[d] = v; s += v;
  }
  float tot = block_sum(s, red);
  float mean = tot * (1.f / 1024.f);
  for (int d = tid; d < 1024; d += 256) nx[n * 1024 + d] = sv[d] / (mean + 1e-6f);
}

// ======================= fc1 (BK=64 swizzled core + LDS-bounce coalesced stores) =========
// 1D grid 2048 = 8 XCD x 32 n-tiles x 8 m-tiles. After the K-loop, As/Bs (32KB) are dead;
// reuse as a [128px][128d] bf16 staging tile (slot-swizzled). All 4 waves write fragments,
// ONE barrier, then 256 threads copy out with 256B-contiguous int4 stores per 16-lane group.
__global__ void __launch_bounds__(256) k_fc1(const short* __restrict__ w1b, const short* __restrict__ tb,
                                             const float* __restrict__ fc1b, const float* __restrict__ grng,
                                             const float* __restrict__ nx, short* __restrict__ u,
                                             int l, int cbase) {
  __shared__ short Ls[16384];
  short* As = Ls;
  short* Bs = Ls + 8192;
  f32x4 acc[4][4];
  int bid = blockIdx.x;
  int xcd = bid & 7, loc = bid >> 3;
  int nt = (xcd << 5) + (loc >> 3);   // 0..255
  int mt = loc & 7;                   // 0..7
  int m0 = mt * 128, n0 = nt * 128;
  gemm_core_k64<256>(w1b + (size_t)l * 262144, tb + (size_t)cbase * 256, m0, n0, As, Bs, acc);
  const int tid = threadIdx.x;
  const int lane = tid & 63, wave = tid >> 6;
  const int wr = wave >> 1, wc = wave & 1, lr = lane & 15, kg = lane >> 4;
  int nimg = (cbase + n0) >> 10;
  // phase 1: GELU + GRN scale -> Ls[pxl][128d] slot-swizzled (<=2-way banks)
#pragma unroll
  for (int mi = 0; mi < 4; ++mi) {
    int dloc = wr * 64 + mi * 16 + kg * 4;         // 0..127
    int dbase = m0 + dloc;
    float b0 = fc1b[l * 1024 + dbase + 0], b1 = fc1b[l * 1024 + dbase + 1];
    float b2 = fc1b[l * 1024 + dbase + 2], b3 = fc1b[l * 1024 + dbase + 3];
    float a0 = 1.f + grng[l * 1024 + dbase + 0] * nx[nimg * 1024 + dbase + 0];
    float a1 = 1.f + grng[l * 1024 + dbase + 1] * nx[nimg * 1024 + dbase + 1];
    float a2 = 1.f + grng[l * 1024 + dbase + 2] * nx[nimg * 1024 + dbase + 2];
    float a3 = 1.f + grng[l * 1024 + dbase + 3] * nx[nimg * 1024 + dbase + 3];
    int s = dloc >> 3, off = dloc & 7;
#pragma unroll
    for (int ni = 0; ni < 4; ++ni) {
      int pxl = wc * 64 + ni * 16 + lr;            // 0..127
      f32x4 v = acc[mi][ni];
      short4 sv;
      sv.x = f2bf(gelu(v[0] + b0) * a0);
      sv.y = f2bf(gelu(v[1] + b1) * a1);
      sv.z = f2bf(gelu(v[2] + b2) * a2);
      sv.w = f2bf(gelu(v[3] + b3) * a3);
      int ss = (s & 8) | ((s ^ (pxl & 7)) & 7);
      *(short4*)&Ls[pxl * 128 + ss * 8 + off] = sv;
    }
  }
  __syncthreads();
  // phase 2: coalesced copy-out; each 16-lane group covers 256B contiguous of u
#pragma unroll
  for (int it = 0; it < 8; ++it) {
    int idx = it * 256 + tid;        // 0..2047 slots of 16B
    int px = idx >> 4, sl = idx & 15;
    int ss = (sl & 8) | ((sl ^ (px & 7)) & 7);
    int4 v = *(const int4*)&Ls[px * 128 + ss * 8];
    *(int4*)&u[(size_t)(n0 + px) * 1024 + m0 + sl * 8] = v;
  }
}

// ======================= fc2 (128x64 tile, XCD-chunked): hb += u@W2^T + b2 + cvec ========
// 1D grid 1024 = 8 XCD x 64 n-tiles x 2 m-tiles
template <int LAST>
__global__ void __launch_bounds__(256) k_fc2(const short* __restrict__ w2b, const short* __restrict__ u,
                                             const float* __restrict__ fc2b, const float* __restrict__ cvec,
                                             short* __restrict__ hb, short* __restrict__ ht,
                                             int l, int cbase) {
  __shared__ short As[4096], Bs[2048];
  f32x4 acc[4][2];
  int bid = blockIdx.x;
  int xcd = bid & 7, loc = bid >> 3;
  int nt = (xcd << 6) + (loc >> 1);   // 0..511
  int mt = loc & 1;                   // 0..1
  int m0 = mt * 128, n0 = nt * 64;
  gemm_core_n64<1024>(w2b + (size_t)l * 262144, u, m0, n0, As, Bs, acc);
  const int lane = threadIdx.x & 63, wave = threadIdx.x >> 6;
  const int wr = wave >> 1, wc = wave & 1, lr = lane & 15, kg = lane >> 4;
#pragma unroll
  for (int mi = 0; mi < 4; ++mi) {
    int ebase = m0 + wr * 64 + mi * 16 + kg * 4;
    float add0 = fc2b[l * 256 + ebase + 0] + cvec[l * 256 + ebase + 0];
    float add1 = fc2b[l * 256 + ebase + 1] + cvec[l * 256 + ebase + 1];
    float add2 = fc2b[l * 256 + ebase + 2] + cvec[l * 256 + ebase + 2];
    float add3 = fc2b[l * 256 + ebase + 3] + cvec[l * 256 + ebase + 3];
#pragma unroll
    for (int ni = 0; ni < 2; ++ni) {
      int P = cbase + n0 + wc * 32 + ni * 16 + lr;
      int n = P >> 10, p = P & 1023;
      f32x4 v = acc[mi][ni];
      short* hp0 = &hb[((size_t)(n * 256 + ebase) << 10) + p];
      float r0 = v[0] + add0 + bf2f(hp0[0]);
      float r1 = v[1] + add1 + bf2f(hp0[1 << 10]);
      float r2 = v[2] + add2 + bf2f(hp0[2 << 10]);
      float r3 = v[3] + add3 + bf2f(hp0[3 << 10]);
      if (LAST) {
        short* hr = &ht[(size_t)P * 256 + ebase];
        hr[0] = f2bf(r0); hr[1] = f2bf(r1); hr[2] = f2bf(r2); hr[3] = f2bf(r3);
      } else {
        hp0[0] = f2bf(r0); hp0[1 << 10] = f2bf(r1); hp0[2 << 10] = f2bf(r2); hp0[3 << 10] = f2bf(r3);
      }
    }
  }
}

// ======================= pred: MFMA GEMM (32 x 65536 x 256) + fused pixel shuffle ========
__global__ void __launch_bounds__(128) k_pred2(const short* __restrict__ ht, const float* __restrict__ pw,
                                               const float* __restrict__ pb, float* __restrict__ out) {
  __shared__ short Aw[32 * 264];
  __shared__ short Bl[256 * 32];
  int tid = threadIdx.x;
  int n0 = blockIdx.x * 256;
  for (int i = tid; i < 8192; i += 128) {
    int o = i >> 8, e = i & 255;
    Aw[o * 264 + e] = f2bf(pw[i]);
  }
  const int lane = tid & 63, wave = tid >> 6;
  const int lr = lane & 15, kg = lane >> 4;
  const int sr = lane >> 2, sc = (lane & 3) * 8;
  f32x4 acc[2][8];
#pragma unroll
  for (int mi = 0; mi < 2; ++mi)
#pragma unroll
    for (int ni = 0; ni < 8; ++ni) acc[mi][ni] = f32x4{0.f, 0.f, 0.f, 0.f};
  __syncthreads();
  for (int k0 = 0; k0 < 256; k0 += 32) {
#pragma unroll
    for (int j = 0; j < 8; ++j) {
      int rb = wave * 128 + j * 16;
      gload16(ht + (size_t)(n0 + rb + sr) * 256 + k0 + sc, Bl + rb * 32);
    }
    __syncthreads();
    bf16x8 af[2], bfr[8];
#pragma unroll
    for (int mi = 0; mi < 2; ++mi) af[mi] = *(const bf16x8*)&Aw[(mi * 16 + lr) * 264 + k0 + kg * 8];
#pragma unroll
    for (int ni = 0; ni < 8; ++ni) bfr[ni] = *(const bf16x8*)&Bl[(wave * 128 + ni * 16 + lr) * 32 + kg * 8];
#pragma unroll
    for (int mi = 0; mi < 2; ++mi)
#pragma unroll
      for (int ni = 0; ni < 8; ++ni)
        acc[mi][ni] = __builtin_amdgcn_mfma_f32_16x16x32_bf16(af[mi], bfr[ni], acc[mi][ni], 0, 0, 0);
    __syncthreads();
  }
#pragma unroll
  for (int mi = 0; mi < 2; ++mi) {
#pragma unroll
    for (int ni = 0; ni < 8; ++ni) {
      int P = n0 + wave * 128 + ni * 16 + lr;
      int n = P >> 10, p = P & 1023;
      int y = p >> 5, xx = p & 31;
      f32x4 v = acc[mi][ni];
#pragma unroll
      for (int r = 0; r < 4; ++r) {
        int o = mi * 16 + kg * 4 + r;
        int s1 = o >> 3, s2 = (o >> 1) & 3, tt = o & 1;
        size_t oi = (((size_t)n * 128 + y * 4 + s1) * 128 + xx * 4 + s2) * 2 + tt;
        out[oi] = v[r] + pb[o];
      }
    }
  }
}

extern "C" void kernel_launch(void* const* d_in, const int* in_sizes, int n_in,
                              void* d_out, int out_size, void* d_ws, size_t ws_size,
                              hipStream_t stream) {
  const float* x    = (const float*)d_in[0];
  const int*   idx  = (const int*)d_in[1];
  const float* hkw  = (const float*)d_in[2];
  const float* hkb  = (const float*)d_in[3];
  const float* dww  = (const float*)d_in[4];
  const float* dwb  = (const float*)d_in[5];
  const float* lng  = (const float*)d_in[6];
  const float* lnb  = (const float*)d_in[7];
  const float* fc1w = (const float*)d_in[8];
  const float* fc1b = (const float*)d_in[9];
  const float* grng = (const float*)d_in[10];
  const float* grnb = (const float*)d_in[11];
  const float* fc2w = (const float*)d_in[12];
  const float* fc2b = (const float*)d_in[13];
  const float* pw   = (const float*)d_in[14];
  const float* pb   = (const float*)d_in[15];
  float* out = (float*)d_out;

  char* ws = (char*)d_ws;
  short* hb   = (short*)(ws);                            // bf16 residual NCHW
  short* tb   = (short*)(ws + (32ull << 20));            // LN'd NHWC (swizzled); ht last layer
  short* u    = (short*)(ws + (64ull << 20));            // 64MB: 32-image hidden chunk
  short* tc   = (short*)(ws + (64ull << 20));            // overlay (conv->ln only)
  short* Wt   = (short*)(ws + (64ull << 20));            // overlay (prologue only)
  short* xTb  = (short*)(ws + (72ull << 20));            // overlay (prologue only)
  short* w1b  = (short*)(ws + (128ull << 20));
  short* w2b  = (short*)(ws + (130ull << 20));
  float* gx   = (float*)(ws + (132ull << 20));
  float* nx   = (float*)(ws + (132ull << 20) + (1 << 18));
  float* cvec = (float*)(ws + (132ull << 20) + (2 << 18));
  int*   flag = (int*)  (ws + (132ull << 20) + (2 << 18) + 4096);

  k_cvt_w<<<4096, 256, 0, stream>>>(fc1w, fc2w, w1b, w2b);
  k_prep_misc<<<dim3(257, 4), 256, 0, stream>>>(grng, grnb, fc2w, flag, cvec);
  k_prep_xt<<<dim3(32, 8, 4), 256, 0, stream>>>(x, xTb);
  k_prep_wt<<<dim3(8, 8, 64), 256, 0, stream>>>(hkw, idx, Wt);
  k_hypm<<<dim3(8, 2, 64), 256, 0, stream>>>(Wt, xTb, idx, hkb, hb);
  for (int l = 0; l < 4; ++l) {
    k_conv<<<dim3(256, 64), 128, 0, stream>>>(hb, dww, dwb, tc, l);
    k_ln<<<dim3(32, 64), 256, 0, stream>>>(tc, lng, lnb, tb, gx, flag, l);
    k_gx1<<<dim3(512, 8), 256, 0, stream>>>(w1b, tb, fc1b, gx, flag, l);
    k_nx<<<64, 256, 0, stream>>>(gx, nx, flag, l);
    for (int c = 0; c < 2; ++c) {
      int cbase = c * 32768;
      k_fc1<<<2048, 256, 0, stream>>>(w1b, tb, fc1b, grng, nx, u, l, cbase);
      if (l < 3)
        k_fc2<0><<<1024, 256, 0, stream>>>(w2b, u, fc2b, cvec, hb, tb, l, cbase);
      else
        k_fc2<1><<<1024, 256, 0, stream>>>(w2b, u, fc2b, cvec, hb, tb, l, cbase);
    }
  }
  k_pred2<<<256, 128, 0, stream>>>(tb, pw, pb, out);
}